// Round 16
// baseline (250.566 us; speedup 1.0000x reference)
//
#include <hip/hip_runtime.h>
#include <hip/hip_bf16.h>
#include <math.h>

#define NB 8
#define NN 4096
#define KK 16
#define MM (NB*NN)
#define CH 32
#define SLOTS 17
#define NE (MM*SLOTS)
#define NCLS 40
#define BIG 3.0e38f
#define CAP 96    // survivors ~20-25 with 17th-lane-min threshold (validated R12-R15)

// Weight table offsets (floats)
#define OW1A 0
#define OB1A 128
#define OW1B 160
#define OB1B 1184
#define OW2A 1216
#define OB2A 2368
#define OW2B 2400
#define OB2B 3424
#define OWC  3456
#define OBC  4736
#define NWTS 4776

// Module-global scratch (~22 MB): no assumptions about ws_size.
__device__ float4 g_pos4[MM];
__device__ float4 g_nrm4[MM];
__device__ int    g_nbr[MM*KK];
__device__ float4 g_fe[NE];          // precomputed PPF per edge
__device__ int    g_jn[NE];          // source node per edge
__device__ float  g_u[MM*CH];
__device__ float  g_wts[NWTS];
__device__ unsigned int g_gmax[NB*CH];
__device__ int    g_isf32;

__device__ __forceinline__ float bf(const __hip_bfloat16 x) { return __bfloat162float(x); }

__device__ __forceinline__ float ldf(const void* p, int i, bool f32) {
  return f32 ? ((const float*)p)[i] : bf(((const __hip_bfloat16*)p)[i]);
}

__device__ __forceinline__ float angf(float ax, float ay, float az,
                                      float bx, float by, float bz) {
  float cx = ay*bz - az*by;
  float cy = az*bx - ax*bz;
  float cz = ax*by - ay*bx;
  float s  = cx*cx + cy*cy + cz*cz;
  float cn = s > 0.f ? sqrtf(s) : 0.f;
  float d  = ax*bx + ay*by + az*bz;
  return (cn > 0.f || d != 0.f) ? atan2f(cn, d) : 0.f;
}

// monotone f32 -> u32 key (order-preserving for all finite floats)
__device__ __forceinline__ unsigned int fkey(float f) {
  unsigned int u = __float_as_uint(f);
  return (u & 0x80000000u) ? ~u : (u | 0x80000000u);
}
__device__ __forceinline__ float funkey(unsigned int k) {
  unsigned int u = (k & 0x80000000u) ? (k ^ 0x80000000u) : ~k;
  return __uint_as_float(u);
}

// ---------------- wprep: parallel dtype vote + weights->fp32 + zero g_gmax ----------------
__global__ __launch_bounds__(256) void wprep_kernel(
    const void* nrm, const void* w1a, const void* b1a, const void* w1b,
    const void* b1b, const void* w2a, const void* b2a, const void* w2b,
    const void* b2b, const void* wc, const void* bc) {
  __shared__ int sflag;
  const int tid = threadIdx.x;
  if (tid < 64) {
    const float* nf = (const float*)nrm;
    const __hip_bfloat16* nh = (const __hip_bfloat16*)nrm;
    float x = nf[3*tid], y = nf[3*tid+1], z = nf[3*tid+2];
    float ss = x*x + y*y + z*z;
    bool okf = (ss > 0.98f && ss < 1.02f);
    float a = bf(nh[3*tid]), b2 = bf(nh[3*tid+1]), c2 = bf(nh[3*tid+2]);
    float sb = a*a + b2*b2 + c2*c2;
    bool okb = (sb > 0.95f && sb < 1.05f);
    unsigned long long mf = __ballot(okf), mb = __ballot(okb);
    if (tid == 0) {
      sflag = (__popcll(mf) >= __popcll(mb)) ? 1 : 0;
      g_isf32 = sflag;
    }
  }
  __syncthreads();
  const bool f32 = sflag != 0;
  for (int i = tid; i < NB*CH; i += 256) g_gmax[i] = 0u;   // max accumulator (x2 >= 0)
  for (int i = tid; i < 128;  i += 256) g_wts[OW1A + i] = ldf(w1a, i, f32);
  for (int i = tid; i < 32;   i += 256) g_wts[OB1A + i] = ldf(b1a, i, f32);
  for (int i = tid; i < 1024; i += 256) g_wts[OW1B + i] = ldf(w1b, i, f32);
  for (int i = tid; i < 32;   i += 256) g_wts[OB1B + i] = ldf(b1b, i, f32);
  for (int i = tid; i < 1152; i += 256) g_wts[OW2A + i] = ldf(w2a, i, f32);
  for (int i = tid; i < 32;   i += 256) g_wts[OB2A + i] = ldf(b2a, i, f32);
  for (int i = tid; i < 1024; i += 256) g_wts[OW2B + i] = ldf(w2b, i, f32);
  for (int i = tid; i < 32;   i += 256) g_wts[OB2B + i] = ldf(b2b, i, f32);
  for (int i = tid; i < 1280; i += 256) g_wts[OWC  + i] = ldf(wc,  i, f32);
  for (int i = tid; i < 40;   i += 256) g_wts[OBC  + i] = ldf(bc,  i, f32);
}

// ---------------- prep: inputs -> float4 (pos.w = |p|^2 f32, filter only) ----------------
__global__ __launch_bounds__(256) void prep_kernel(const void* __restrict__ pos,
                                                   const void* __restrict__ nrm) {
  const bool f32 = g_isf32 != 0;
  int i = blockIdx.x*256 + threadIdx.x;
  float x = ldf(pos, 3*i, f32), y = ldf(pos, 3*i+1, f32), z = ldf(pos, 3*i+2, f32);
  float sq = x*x + y*y + z*z;
  g_pos4[i] = make_float4(x, y, z, sq);
  float a = ldf(nrm, 3*i, f32), b = ldf(nrm, 3*i+1, f32), c = ldf(nrm, 3*i+2, f32);
  g_nrm4[i] = make_float4(a, b, c, 0.f);
}

// ---------------- kNN: 512-thread blocks, SoA xyz tile, interleaved bisection -----------
// (structure validated R12-R15; this round: the 8 queries' 32-step ballot binary
// searches are interleaved (step outer, query inner) so the 8 dependent
// v_cmp->s_bcnt1->s_cselect chains pipeline instead of serializing.)
__global__ __launch_bounds__(512) void knn_kernel() {
  __shared__ float sx[NN], sy[NN], sz[NN];          // 49152 B (SoA xyz tile)
  __shared__ unsigned short ilst[64][CAP];          // 12288 B
  __shared__ double dlst[8][CAP];                   //  6144 B
  __shared__ int    cnt[64];
  const int tid  = threadIdx.x;
  const int w    = tid >> 6, lane = tid & 63;
  const int blk  = blockIdx.x;
  const int b    = blk >> 6;                        // 64 blocks per batch
  const int qbw  = ((blk & 63) << 6) | (w << 3);    // first of this wave's 8 queries
  const float4* bp = g_pos4 + b*NN;

  #pragma unroll
  for (int k = 0; k < 8; ++k) {
    int idx = k*512 + tid;
    float4 o = bp[idx];
    sx[idx] = o.x; sy[idx] = o.y; sz[idx] = o.z;
  }
  __syncthreads();                                  // the only barrier

  float q2x[8], q2y[8], q2z[8];
  #pragma unroll
  for (int qq = 0; qq < 8; ++qq) {
    int qi = qbw + qq;
    q2x[qq] = -2.f*sx[qi]; q2y[qq] = -2.f*sy[qi]; q2z[qq] = -2.f*sz[qi];
  }

  // ---- pass 1: per-lane column mins for 8 queries (self included) ----
  float mn[8];
  #pragma unroll
  for (int qq = 0; qq < 8; ++qq) mn[qq] = BIG;
  #pragma unroll 4
  for (int it = 0; it < 64; ++it) {
    int idx = it*64 + lane;
    float ox = sx[idx], oy = sy[idx], oz = sz[idx];
    float ow = __builtin_fmaf(oz, oz, __builtin_fmaf(oy, oy, ox*ox));
    #pragma unroll
    for (int qq = 0; qq < 8; ++qq) {
      float d = __builtin_fmaf(q2x[qq], ox,
                __builtin_fmaf(q2y[qq], oy,
                __builtin_fmaf(q2z[qq], oz, ow)));
      mn[qq] = fminf(mn[qq], d);
    }
  }

  // ---- threshold: 17th-smallest lane-min, 8 interleaved ballot bisections ----
  // self d2' = -|q|^2 is the strict global min (Cauchy-Schwarz) => >=16 non-self <= T.
  unsigned int key[8], lo[8], hi[8];
  #pragma unroll
  for (int qq = 0; qq < 8; ++qq) { key[qq] = fkey(mn[qq]); lo[qq] = 0u; hi[qq] = 0xFFFFFFFFu; }
  #pragma unroll 1
  for (int s = 0; s < 32; ++s) {
    #pragma unroll
    for (int qq = 0; qq < 8; ++qq) {
      unsigned int mid = lo[qq] + ((hi[qq] - lo[qq]) >> 1);
      int c = (int)__popcll(__ballot(key[qq] <= mid));
      if (c >= 17) hi[qq] = mid; else lo[qq] = mid + 1;
    }
  }
  float Tf[8];
  #pragma unroll
  for (int qq = 0; qq < 8; ++qq) {
    float T = funkey(hi[qq]);                       // exact 17th smallest
    Tf[qq] = T + 4e-5f + 1e-5f*fabsf(T);            // margin >> f32 d2' abs error
  }

  if (lane < 8) cnt[(w<<3) | lane] = 0;             // wave-private counters

  // ---- pass 2: recompute + sparse collect into wave-private lists ----
  #pragma unroll 4
  for (int it = 0; it < 64; ++it) {
    int idx = it*64 + lane;
    float ox = sx[idx], oy = sy[idx], oz = sz[idx];
    float ow = __builtin_fmaf(oz, oz, __builtin_fmaf(oy, oy, ox*ox));
    #pragma unroll
    for (int qq = 0; qq < 8; ++qq) {
      float d = __builtin_fmaf(q2x[qq], ox,
                __builtin_fmaf(q2y[qq], oy,
                __builtin_fmaf(q2z[qq], oz, ow)));
      if (d <= Tf[qq] && idx != qbw + qq) {
        int p = atomicAdd(&cnt[(w<<3)|qq], 1);
        if (p < CAP) ilst[(w<<3)|qq][p] = (unsigned short)idx;
      }
    }
  }

  // ---- per query: f64 rescore (numpy-exact, from LDS tile) + exact rank ----
  #pragma unroll 1
  for (int qq = 0; qq < 8; ++qq) {
    const int qi = qbw + qq;
    const int m = min(cnt[(w<<3)|qq], CAP);
    const double mx = (double)sx[qi], my_ = (double)sy[qi], mz = (double)sz[qi];
    const double sqme = (mx*mx + my_*my_) + mz*mz;
    for (int e = lane; e < m; e += 64) {
      int ci = ilst[(w<<3)|qq][e];
      double ox = (double)sx[ci], oy = (double)sy[ci], oz = (double)sz[ci];
      double sqo = (ox*ox + oy*oy) + oz*oz;
      double dt  = (mx*ox + my_*oy) + mz*oz;
      dlst[w][e] = (sqme + sqo) - 2.0*dt;
    }
    for (int e = lane; e < m; e += 64) {
      double myd = dlst[w][e];
      int myi = ilst[(w<<3)|qq][e];
      int rank = 0;
      for (int o = 0; o < m; ++o) {                 // broadcast LDS reads
        double od = dlst[w][o];
        int oi = ilst[(w<<3)|qq][o];
        rank += (od < myd) || (od == myd && oi < myi);
      }
      if (rank < KK) g_nbr[(b*NN + qi)*KK + rank] = b*NN + myi;
    }
  }
}

// ---------------- edges: PPF features computed ONCE, full occupancy ----------------
__global__ __launch_bounds__(256) void edges_kernel() {
  int e = blockIdx.x*256 + threadIdx.x;             // NE = MM*17 edges
  int i = e / SLOTS, slot = e - i*SLOTS;
  int j = (slot < KK) ? g_nbr[i*KK + slot] : i;     // slot 16 = self-loop
  g_jn[e] = j;
  float4 pi = g_pos4[i], ni = g_nrm4[i];
  float4 pj = g_pos4[j], nj = g_nrm4[j];
  float px = pj.x - pi.x, py = pj.y - pi.y, pz = pj.z - pi.z;
  float s = px*px + py*py + pz*pz;
  float f0 = s > 0.f ? sqrtf(s) : 0.f;
  float f1 = angf(ni.x, ni.y, ni.z, px, py, pz);
  float f2 = angf(nj.x, nj.y, nj.z, px, py, pz);
  float f3 = angf(ni.x, ni.y, ni.z, nj.x, nj.y, nj.z);
  g_fe[e] = make_float4(f0, f1, f2, f3);
}

// ---------------- conv1: 8 nodes/block, fused u = relu(max(msg1)) @ w2a[0:32] ----------------
__global__ __launch_bounds__(256) void conv1_kernel() {
  __shared__ __align__(16) float fe[136][4];
  __shared__ __align__(16) float h1s[8*SLOTS*CH];
  __shared__ __align__(16) float xs[8][CH];
  const int tid = threadIdx.x;
  const int c = tid & 31;
  const int node0 = blockIdx.x << 3;
  float w1a_c[4], w1b_c[32], w2a_c[32];
  #pragma unroll
  for (int f = 0; f < 4; ++f)  w1a_c[f] = g_wts[OW1A + f*CH + c];
  #pragma unroll
  for (int k = 0; k < 32; ++k) w1b_c[k] = g_wts[OW1B + k*CH + c];
  #pragma unroll
  for (int k = 0; k < 32; ++k) w2a_c[k] = g_wts[OW2A + k*CH + c];
  const float b1a_c = g_wts[OB1A + c], b1b_c = g_wts[OB1B + c];

  if (tid < 136) *(float4*)fe[tid] = g_fe[node0*SLOTS + tid];  // precomputed PPF
  __syncthreads();
  #pragma unroll
  for (int it = 0; it < 17; ++it) {
    int idx = it*256 + tid;                   // (e, c) with c == tid&31
    int e = idx >> 5;
    float4 f4 = *(const float4*)fe[e];
    float h = b1a_c + f4.x*w1a_c[0] + f4.y*w1a_c[1] + f4.z*w1a_c[2] + f4.w*w1a_c[3];
    h1s[idx] = fmaxf(h, 0.f);
  }
  __syncthreads();
  const int ns = tid >> 5;
  const int i  = node0 + ns;
  float acc = -BIG;
  #pragma unroll
  for (int slot = 0; slot < SLOTS; ++slot) {
    const float* hr = &h1s[(ns*SLOTS + slot)*CH];
    float msg = b1b_c;
    #pragma unroll
    for (int k4 = 0; k4 < 8; ++k4) {
      float4 h4 = *(const float4*)(hr + 4*k4);
      msg += h4.x*w1b_c[4*k4] + h4.y*w1b_c[4*k4+1] + h4.z*w1b_c[4*k4+2] + h4.w*w1b_c[4*k4+3];
    }
    acc = fmaxf(acc, msg);
  }
  xs[ns][c] = fmaxf(acc, 0.f);                // x1 = relu(segment_max)
  __syncthreads();
  float uu = 0.f;
  #pragma unroll
  for (int k4 = 0; k4 < 8; ++k4) {
    float4 x4 = *(const float4*)&xs[ns][4*k4];
    uu += x4.x*w2a_c[4*k4] + x4.y*w2a_c[4*k4+1] + x4.z*w2a_c[4*k4+2] + x4.w*w2a_c[4*k4+3];
  }
  g_u[i*CH + c] = uu;                         // u = x1 @ w2a[0:32,:]
}

// ---------------- conv2 (+ fused max-pool epilogue; x2 never materialized) --------------
__global__ __launch_bounds__(256) void conv2_kernel() {
  __shared__ __align__(16) float fe[136][4];
  __shared__ int jn[136];
  __shared__ __align__(16) float h2s[8*SLOTS*CH];
  __shared__ float xs[8][CH];
  const int tid = threadIdx.x;
  const int c = tid & 31;
  const int node0 = blockIdx.x << 3;
  float w2aL_c[4], w2b_c[32];
  #pragma unroll
  for (int f = 0; f < 4; ++f)  w2aL_c[f] = g_wts[OW2A + (CH + f)*CH + c];
  #pragma unroll
  for (int k = 0; k < 32; ++k) w2b_c[k] = g_wts[OW2B + k*CH + c];
  const float b2a_c = g_wts[OB2A + c], b2b_c = g_wts[OB2B + c];

  if (tid < 136) {
    *(float4*)fe[tid] = g_fe[node0*SLOTS + tid];    // precomputed PPF
    jn[tid] = g_jn[node0*SLOTS + tid];
  }
  __syncthreads();
  #pragma unroll
  for (int it = 0; it < 17; ++it) {
    int idx = it*256 + tid;
    int e = idx >> 5;
    float4 f4 = *(const float4*)fe[e];
    float uv = g_u[jn[e]*CH + c];             // x_j @ w2a[0:32] precomputed
    float h = b2a_c + uv + f4.x*w2aL_c[0] + f4.y*w2aL_c[1] + f4.z*w2aL_c[2] + f4.w*w2aL_c[3];
    h2s[idx] = fmaxf(h, 0.f);
  }
  __syncthreads();
  const int ns = tid >> 5;
  float acc = -BIG;
  #pragma unroll
  for (int slot = 0; slot < SLOTS; ++slot) {
    const float* hr = &h2s[(ns*SLOTS + slot)*CH];
    float msg = b2b_c;
    #pragma unroll
    for (int k4 = 0; k4 < 8; ++k4) {
      float4 h4 = *(const float4*)(hr + 4*k4);
      msg += h4.x*w2b_c[4*k4] + h4.y*w2b_c[4*k4+1] + h4.z*w2b_c[4*k4+2] + h4.w*w2b_c[4*k4+3];
    }
    acc = fmaxf(acc, msg);
  }
  xs[ns][c] = fmaxf(acc, 0.f);                // x2 = relu(segment_max)
  __syncthreads();
  if (tid < CH) {                             // fused block max + global atomicMax
    float m2 = xs[0][c];
    #pragma unroll
    for (int r = 1; r < 8; ++r) m2 = fmaxf(m2, xs[r][c]);
    int g = blockIdx.x >> 9;                  // node0/NN
    atomicMax(&g_gmax[g*CH + c], __float_as_uint(m2));  // exact for floats >= 0
  }
}

// ---------------- head (float32 output) ----------------
__global__ __launch_bounds__(64) void head_kernel(float* __restrict__ out) {
  const int g = blockIdx.x;
  const int co = threadIdx.x;
  if (co < NCLS) {
    float s = g_wts[OBC + co];
    #pragma unroll
    for (int f = 0; f < CH; ++f)
      s += __uint_as_float(g_gmax[g*CH + f]) * g_wts[OWC + f*NCLS + co];
    out[g*NCLS + co] = s;                     // float32 out (reference dtype)
  }
}

extern "C" void kernel_launch(void* const* d_in, const int* in_sizes, int n_in,
                              void* d_out, int out_size, void* d_ws, size_t ws_size,
                              hipStream_t stream) {
  const void* pos = d_in[0];
  const void* nrm = d_in[1];
  // d_in[2] = batch (int32) -- unused, batches are uniform
  const void* w1a = d_in[3];
  const void* b1a = d_in[4];
  const void* w1b = d_in[5];
  const void* b1b = d_in[6];
  const void* w2a = d_in[7];
  const void* b2a = d_in[8];
  const void* w2b = d_in[9];
  const void* b2b = d_in[10];
  const void* wc  = d_in[11];
  const void* bc  = d_in[12];

  wprep_kernel<<<1,       256, 0, stream>>>(nrm, w1a, b1a, w1b, b1b, w2a, b2a, w2b, b2b, wc, bc);
  prep_kernel <<<MM/256,  256, 0, stream>>>(pos, nrm);
  knn_kernel  <<<MM/64,   512, 0, stream>>>();
  edges_kernel<<<NE/256,  256, 0, stream>>>();
  conv1_kernel<<<MM/8,    256, 0, stream>>>();
  conv2_kernel<<<MM/8,    256, 0, stream>>>();
  head_kernel <<<NB,      64,  0, stream>>>((float*)d_out);
}

// Round 17
// 248.916 us; speedup vs baseline: 1.0066x; 1.0066x over previous
//
#include <hip/hip_runtime.h>
#include <hip/hip_bf16.h>
#include <math.h>

#define NB 8
#define NN 4096
#define KK 16
#define MM (NB*NN)
#define CH 32
#define SLOTS 17
#define NCLS 40
#define BIG 3.0e38f
#define CAP 96    // survivors ~20-25 with 17th-lane-min threshold (validated R12-R16)

// Weight table offsets (floats)
#define OW1A 0
#define OB1A 128
#define OW1B 160
#define OB1B 1184
#define OW2A 1216
#define OB2A 2368
#define OW2B 2400
#define OB2B 3424
#define OWC  3456
#define OBC  4736
#define NWTS 4776

// Module-global scratch (~11 MB): no assumptions about ws_size.
__device__ float4 g_pos4[MM];
__device__ float4 g_nrm4[MM];
__device__ int    g_nbr[MM*KK];
__device__ float  g_u[MM*CH];
__device__ float  g_wts[NWTS];
__device__ unsigned int g_gmax[NB*CH];
__device__ int    g_isf32;

__device__ __forceinline__ float bf(const __hip_bfloat16 x) { return __bfloat162float(x); }

__device__ __forceinline__ float ldf(const void* p, int i, bool f32) {
  return f32 ? ((const float*)p)[i] : bf(((const __hip_bfloat16*)p)[i]);
}

__device__ __forceinline__ float angf(float ax, float ay, float az,
                                      float bx, float by, float bz) {
  float cx = ay*bz - az*by;
  float cy = az*bx - ax*bz;
  float cz = ax*by - ay*bx;
  float s  = cx*cx + cy*cy + cz*cz;
  float cn = s > 0.f ? sqrtf(s) : 0.f;
  float d  = ax*bx + ay*by + az*bz;
  return (cn > 0.f || d != 0.f) ? atan2f(cn, d) : 0.f;
}

__device__ __forceinline__ void ppf4(const float4 pi, const float4 ni,
                                     const float4 pj, const float4 nj, float* f) {
  float px = pj.x - pi.x, py = pj.y - pi.y, pz = pj.z - pi.z;
  float s = px*px + py*py + pz*pz;
  f[0] = s > 0.f ? sqrtf(s) : 0.f;
  f[1] = angf(ni.x, ni.y, ni.z, px, py, pz);
  f[2] = angf(nj.x, nj.y, nj.z, px, py, pz);
  f[3] = angf(ni.x, ni.y, ni.z, nj.x, nj.y, nj.z);
}

// monotone f32 -> u32 key (order-preserving for all finite floats)
__device__ __forceinline__ unsigned int fkey(float f) {
  unsigned int u = __float_as_uint(f);
  return (u & 0x80000000u) ? ~u : (u | 0x80000000u);
}
__device__ __forceinline__ float funkey(unsigned int k) {
  unsigned int u = (k & 0x80000000u) ? (k ^ 0x80000000u) : ~k;
  return __uint_as_float(u);
}

// ---------------- wprep: parallel dtype vote + weights->fp32 + zero g_gmax ----------------
__global__ __launch_bounds__(256) void wprep_kernel(
    const void* nrm, const void* w1a, const void* b1a, const void* w1b,
    const void* b1b, const void* w2a, const void* b2a, const void* w2b,
    const void* b2b, const void* wc, const void* bc) {
  __shared__ int sflag;
  const int tid = threadIdx.x;
  if (tid < 64) {
    const float* nf = (const float*)nrm;
    const __hip_bfloat16* nh = (const __hip_bfloat16*)nrm;
    float x = nf[3*tid], y = nf[3*tid+1], z = nf[3*tid+2];
    float ss = x*x + y*y + z*z;
    bool okf = (ss > 0.98f && ss < 1.02f);
    float a = bf(nh[3*tid]), b2 = bf(nh[3*tid+1]), c2 = bf(nh[3*tid+2]);
    float sb = a*a + b2*b2 + c2*c2;
    bool okb = (sb > 0.95f && sb < 1.05f);
    unsigned long long mf = __ballot(okf), mb = __ballot(okb);
    if (tid == 0) {
      sflag = (__popcll(mf) >= __popcll(mb)) ? 1 : 0;
      g_isf32 = sflag;
    }
  }
  __syncthreads();
  const bool f32 = sflag != 0;
  for (int i = tid; i < NB*CH; i += 256) g_gmax[i] = 0u;   // max accumulator (x2 >= 0)
  for (int i = tid; i < 128;  i += 256) g_wts[OW1A + i] = ldf(w1a, i, f32);
  for (int i = tid; i < 32;   i += 256) g_wts[OB1A + i] = ldf(b1a, i, f32);
  for (int i = tid; i < 1024; i += 256) g_wts[OW1B + i] = ldf(w1b, i, f32);
  for (int i = tid; i < 32;   i += 256) g_wts[OB1B + i] = ldf(b1b, i, f32);
  for (int i = tid; i < 1152; i += 256) g_wts[OW2A + i] = ldf(w2a, i, f32);
  for (int i = tid; i < 32;   i += 256) g_wts[OB2A + i] = ldf(b2a, i, f32);
  for (int i = tid; i < 1024; i += 256) g_wts[OW2B + i] = ldf(w2b, i, f32);
  for (int i = tid; i < 32;   i += 256) g_wts[OB2B + i] = ldf(b2b, i, f32);
  for (int i = tid; i < 1280; i += 256) g_wts[OWC  + i] = ldf(wc,  i, f32);
  for (int i = tid; i < 40;   i += 256) g_wts[OBC  + i] = ldf(bc,  i, f32);
}

// ---------------- prep: inputs -> float4 (pos.w = |p|^2 f32, filter only) ----------------
__global__ __launch_bounds__(256) void prep_kernel(const void* __restrict__ pos,
                                                   const void* __restrict__ nrm) {
  const bool f32 = g_isf32 != 0;
  int i = blockIdx.x*256 + threadIdx.x;
  float x = ldf(pos, 3*i, f32), y = ldf(pos, 3*i+1, f32), z = ldf(pos, 3*i+2, f32);
  float sq = x*x + y*y + z*z;
  g_pos4[i] = make_float4(x, y, z, sq);
  float a = ldf(nrm, 3*i, f32), b = ldf(nrm, 3*i+1, f32), c = ldf(nrm, 3*i+2, f32);
  g_nrm4[i] = make_float4(a, b, c, 0.f);
}

// ---------------- kNN: 512-thread blocks, SoA xyz tile, interleaved bisection -----------
// Structure validated R12-R16. Filter d2' = |o|^2 - 2*dot(q,o) (|o|^2 recomputed,
// bit-identical both passes; margin covers f32 error). Threshold = exact
// 17th-smallest per-lane column-min via 8 interleaved 32-step ballot bisections
// (self included: self d2' = -|q|^2 is the strict global min => >=16 non-self <= T).
// Pass 2 recomputes + collects into wave-private lists; f64 rescore (numpy-exact
// association) + exact lexicographic (d2_f64, idx) rank. One barrier total.
__global__ __launch_bounds__(512) void knn_kernel() {
  __shared__ float sx[NN], sy[NN], sz[NN];          // 49152 B (SoA xyz tile)
  __shared__ unsigned short ilst[64][CAP];          // 12288 B
  __shared__ double dlst[8][CAP];                   //  6144 B
  __shared__ int    cnt[64];
  const int tid  = threadIdx.x;
  const int w    = tid >> 6, lane = tid & 63;
  const int blk  = blockIdx.x;
  const int b    = blk >> 6;                        // 64 blocks per batch
  const int qbw  = ((blk & 63) << 6) | (w << 3);    // first of this wave's 8 queries
  const float4* bp = g_pos4 + b*NN;

  #pragma unroll
  for (int k = 0; k < 8; ++k) {
    int idx = k*512 + tid;
    float4 o = bp[idx];
    sx[idx] = o.x; sy[idx] = o.y; sz[idx] = o.z;
  }
  __syncthreads();                                  // the only barrier

  float q2x[8], q2y[8], q2z[8];
  #pragma unroll
  for (int qq = 0; qq < 8; ++qq) {
    int qi = qbw + qq;
    q2x[qq] = -2.f*sx[qi]; q2y[qq] = -2.f*sy[qi]; q2z[qq] = -2.f*sz[qi];
  }

  // ---- pass 1: per-lane column mins for 8 queries (self included) ----
  float mn[8];
  #pragma unroll
  for (int qq = 0; qq < 8; ++qq) mn[qq] = BIG;
  #pragma unroll 4
  for (int it = 0; it < 64; ++it) {
    int idx = it*64 + lane;
    float ox = sx[idx], oy = sy[idx], oz = sz[idx];
    float ow = __builtin_fmaf(oz, oz, __builtin_fmaf(oy, oy, ox*ox));
    #pragma unroll
    for (int qq = 0; qq < 8; ++qq) {
      float d = __builtin_fmaf(q2x[qq], ox,
                __builtin_fmaf(q2y[qq], oy,
                __builtin_fmaf(q2z[qq], oz, ow)));
      mn[qq] = fminf(mn[qq], d);
    }
  }

  // ---- threshold: 17th-smallest lane-min, 8 interleaved ballot bisections ----
  unsigned int key[8], lo[8], hi[8];
  #pragma unroll
  for (int qq = 0; qq < 8; ++qq) { key[qq] = fkey(mn[qq]); lo[qq] = 0u; hi[qq] = 0xFFFFFFFFu; }
  #pragma unroll 1
  for (int s = 0; s < 32; ++s) {
    #pragma unroll
    for (int qq = 0; qq < 8; ++qq) {
      unsigned int mid = lo[qq] + ((hi[qq] - lo[qq]) >> 1);
      int c = (int)__popcll(__ballot(key[qq] <= mid));
      if (c >= 17) hi[qq] = mid; else lo[qq] = mid + 1;
    }
  }
  float Tf[8];
  #pragma unroll
  for (int qq = 0; qq < 8; ++qq) {
    float T = funkey(hi[qq]);                       // exact 17th smallest
    Tf[qq] = T + 4e-5f + 1e-5f*fabsf(T);            // margin >> f32 d2' abs error
  }

  if (lane < 8) cnt[(w<<3) | lane] = 0;             // wave-private counters

  // ---- pass 2: recompute + sparse collect into wave-private lists ----
  #pragma unroll 4
  for (int it = 0; it < 64; ++it) {
    int idx = it*64 + lane;
    float ox = sx[idx], oy = sy[idx], oz = sz[idx];
    float ow = __builtin_fmaf(oz, oz, __builtin_fmaf(oy, oy, ox*ox));
    #pragma unroll
    for (int qq = 0; qq < 8; ++qq) {
      float d = __builtin_fmaf(q2x[qq], ox,
                __builtin_fmaf(q2y[qq], oy,
                __builtin_fmaf(q2z[qq], oz, ow)));
      if (d <= Tf[qq] && idx != qbw + qq) {
        int p = atomicAdd(&cnt[(w<<3)|qq], 1);
        if (p < CAP) ilst[(w<<3)|qq][p] = (unsigned short)idx;
      }
    }
  }

  // ---- per query: f64 rescore (numpy-exact, from LDS tile) + exact rank ----
  #pragma unroll 1
  for (int qq = 0; qq < 8; ++qq) {
    const int qi = qbw + qq;
    const int m = min(cnt[(w<<3)|qq], CAP);
    const double mx = (double)sx[qi], my_ = (double)sy[qi], mz = (double)sz[qi];
    const double sqme = (mx*mx + my_*my_) + mz*mz;
    for (int e = lane; e < m; e += 64) {
      int ci = ilst[(w<<3)|qq][e];
      double ox = (double)sx[ci], oy = (double)sy[ci], oz = (double)sz[ci];
      double sqo = (ox*ox + oy*oy) + oz*oz;
      double dt  = (mx*ox + my_*oy) + mz*oz;
      dlst[w][e] = (sqme + sqo) - 2.0*dt;
    }
    for (int e = lane; e < m; e += 64) {
      double myd = dlst[w][e];
      int myi = ilst[(w<<3)|qq][e];
      int rank = 0;
      for (int o = 0; o < m; ++o) {                 // broadcast LDS reads
        double od = dlst[w][o];
        int oi = ilst[(w<<3)|qq][o];
        rank += (od < myd) || (od == myd && oi < myi);
      }
      if (rank < KK) g_nbr[(b*NN + qi)*KK + rank] = b*NN + myi;
    }
  }
}

// ---------------- conv1: 8 nodes/block, fused u = relu(max(msg1)) @ w2a[0:32] ----------------
__global__ __launch_bounds__(256) void conv1_kernel() {
  __shared__ __align__(16) float fe[136][4];
  __shared__ __align__(16) float h1s[8*SLOTS*CH];
  __shared__ __align__(16) float xs[8][CH];
  const int tid = threadIdx.x;
  const int c = tid & 31;
  const int node0 = blockIdx.x << 3;
  float w1a_c[4], w1b_c[32], w2a_c[32];
  #pragma unroll
  for (int f = 0; f < 4; ++f)  w1a_c[f] = g_wts[OW1A + f*CH + c];
  #pragma unroll
  for (int k = 0; k < 32; ++k) w1b_c[k] = g_wts[OW1B + k*CH + c];
  #pragma unroll
  for (int k = 0; k < 32; ++k) w2a_c[k] = g_wts[OW2A + k*CH + c];
  const float b1a_c = g_wts[OB1A + c], b1b_c = g_wts[OB1B + c];

  if (tid < 136) {
    int ns = tid / 17, slot = tid - ns*17;
    int i = node0 + ns;
    int j = (slot < KK) ? g_nbr[i*KK + slot] : i;   // slot 16 = self-loop
    ppf4(g_pos4[i], g_nrm4[i], g_pos4[j], g_nrm4[j], fe[tid]);
  }
  __syncthreads();
  #pragma unroll
  for (int it = 0; it < 17; ++it) {
    int idx = it*256 + tid;                   // (e, c) with c == tid&31
    int e = idx >> 5;
    float4 f4 = *(const float4*)fe[e];
    float h = b1a_c + f4.x*w1a_c[0] + f4.y*w1a_c[1] + f4.z*w1a_c[2] + f4.w*w1a_c[3];
    h1s[idx] = fmaxf(h, 0.f);
  }
  __syncthreads();
  const int ns = tid >> 5;
  const int i  = node0 + ns;
  float acc = -BIG;
  #pragma unroll
  for (int slot = 0; slot < SLOTS; ++slot) {
    const float* hr = &h1s[(ns*SLOTS + slot)*CH];
    float msg = b1b_c;
    #pragma unroll
    for (int k4 = 0; k4 < 8; ++k4) {
      float4 h4 = *(const float4*)(hr + 4*k4);
      msg += h4.x*w1b_c[4*k4] + h4.y*w1b_c[4*k4+1] + h4.z*w1b_c[4*k4+2] + h4.w*w1b_c[4*k4+3];
    }
    acc = fmaxf(acc, msg);
  }
  xs[ns][c] = fmaxf(acc, 0.f);                // x1 = relu(segment_max)
  __syncthreads();
  float uu = 0.f;
  #pragma unroll
  for (int k4 = 0; k4 < 8; ++k4) {
    float4 x4 = *(const float4*)&xs[ns][4*k4];
    uu += x4.x*w2a_c[4*k4] + x4.y*w2a_c[4*k4+1] + x4.z*w2a_c[4*k4+2] + x4.w*w2a_c[4*k4+3];
  }
  g_u[i*CH + c] = uu;                         // u = x1 @ w2a[0:32,:]
}

// ---------------- conv2 (+ fused max-pool epilogue; x2 never materialized) --------------
__global__ __launch_bounds__(256) void conv2_kernel() {
  __shared__ __align__(16) float fe[136][4];
  __shared__ int jn[136];
  __shared__ __align__(16) float h2s[8*SLOTS*CH];
  __shared__ float xs[8][CH];
  const int tid = threadIdx.x;
  const int c = tid & 31;
  const int node0 = blockIdx.x << 3;
  float w2aL_c[4], w2b_c[32];
  #pragma unroll
  for (int f = 0; f < 4; ++f)  w2aL_c[f] = g_wts[OW2A + (CH + f)*CH + c];
  #pragma unroll
  for (int k = 0; k < 32; ++k) w2b_c[k] = g_wts[OW2B + k*CH + c];
  const float b2a_c = g_wts[OB2A + c], b2b_c = g_wts[OB2B + c];

  if (tid < 136) {
    int ns = tid / 17, slot = tid - ns*17;
    int i = node0 + ns;
    int j = (slot < KK) ? g_nbr[i*KK + slot] : i;
    jn[tid] = j;
    ppf4(g_pos4[i], g_nrm4[i], g_pos4[j], g_nrm4[j], fe[tid]);
  }
  __syncthreads();
  #pragma unroll
  for (int it = 0; it < 17; ++it) {
    int idx = it*256 + tid;
    int e = idx >> 5;
    float4 f4 = *(const float4*)fe[e];
    float uv = g_u[jn[e]*CH + c];             // x_j @ w2a[0:32] precomputed
    float h = b2a_c + uv + f4.x*w2aL_c[0] + f4.y*w2aL_c[1] + f4.z*w2aL_c[2] + f4.w*w2aL_c[3];
    h2s[idx] = fmaxf(h, 0.f);
  }
  __syncthreads();
  const int ns = tid >> 5;
  float acc = -BIG;
  #pragma unroll
  for (int slot = 0; slot < SLOTS; ++slot) {
    const float* hr = &h2s[(ns*SLOTS + slot)*CH];
    float msg = b2b_c;
    #pragma unroll
    for (int k4 = 0; k4 < 8; ++k4) {
      float4 h4 = *(const float4*)(hr + 4*k4);
      msg += h4.x*w2b_c[4*k4] + h4.y*w2b_c[4*k4+1] + h4.z*w2b_c[4*k4+2] + h4.w*w2b_c[4*k4+3];
    }
    acc = fmaxf(acc, msg);
  }
  xs[ns][c] = fmaxf(acc, 0.f);                // x2 = relu(segment_max)
  __syncthreads();
  if (tid < CH) {                             // fused block max + global atomicMax
    float m2 = xs[0][c];
    #pragma unroll
    for (int r = 1; r < 8; ++r) m2 = fmaxf(m2, xs[r][c]);
    int g = blockIdx.x >> 9;                  // node0/NN
    atomicMax(&g_gmax[g*CH + c], __float_as_uint(m2));  // exact for floats >= 0
  }
}

// ---------------- head (float32 output) ----------------
__global__ __launch_bounds__(64) void head_kernel(float* __restrict__ out) {
  const int g = blockIdx.x;
  const int co = threadIdx.x;
  if (co < NCLS) {
    float s = g_wts[OBC + co];
    #pragma unroll
    for (int f = 0; f < CH; ++f)
      s += __uint_as_float(g_gmax[g*CH + f]) * g_wts[OWC + f*NCLS + co];
    out[g*NCLS + co] = s;                     // float32 out (reference dtype)
  }
}

extern "C" void kernel_launch(void* const* d_in, const int* in_sizes, int n_in,
                              void* d_out, int out_size, void* d_ws, size_t ws_size,
                              hipStream_t stream) {
  const void* pos = d_in[0];
  const void* nrm = d_in[1];
  // d_in[2] = batch (int32) -- unused, batches are uniform
  const void* w1a = d_in[3];
  const void* b1a = d_in[4];
  const void* w1b = d_in[5];
  const void* b1b = d_in[6];
  const void* w2a = d_in[7];
  const void* b2a = d_in[8];
  const void* w2b = d_in[9];
  const void* b2b = d_in[10];
  const void* wc  = d_in[11];
  const void* bc  = d_in[12];

  wprep_kernel<<<1,      256, 0, stream>>>(nrm, w1a, b1a, w1b, b1b, w2a, b2a, w2b, b2b, wc, bc);
  prep_kernel <<<MM/256, 256, 0, stream>>>(pos, nrm);
  knn_kernel  <<<MM/64,  512, 0, stream>>>();
  conv1_kernel<<<MM/8,   256, 0, stream>>>();
  conv2_kernel<<<MM/8,   256, 0, stream>>>();
  head_kernel <<<NB,     64,  0, stream>>>((float*)d_out);
}

// Round 18
// 228.319 us; speedup vs baseline: 1.0974x; 1.0902x over previous
//
#include <hip/hip_runtime.h>
#include <hip/hip_bf16.h>
#include <math.h>

#define NB 8
#define NN 4096
#define KK 16
#define MM (NB*NN)
#define CH 32
#define SLOTS 17
#define NCLS 40
#define BIG 3.0e38f
#define CAP 96    // survivors ~20-25 with 17th-lane-min threshold (validated R12-R17)
#define NBLK2 (MM/8)   // conv2 block count (8 nodes/block)

// Weight table offsets (floats)
#define OW1A 0
#define OB1A 128
#define OW1B 160
#define OB1B 1184
#define OW2A 1216
#define OB2A 2368
#define OW2B 2400
#define OB2B 3424
#define OWC  3456
#define OBC  4736
#define NWTS 4776

// Module-global scratch (~12 MB): no assumptions about ws_size.
__device__ float4 g_pos4[MM];
__device__ float4 g_nrm4[MM];
__device__ int    g_nbr[MM*KK];
__device__ float  g_u[MM*CH];
__device__ float  g_bmax[NBLK2*CH];   // per-conv2-block channel maxima (no atomics)
__device__ float  g_wts[NWTS];
__device__ int    g_isf32;

__device__ __forceinline__ float bf(const __hip_bfloat16 x) { return __bfloat162float(x); }

__device__ __forceinline__ float ldf(const void* p, int i, bool f32) {
  return f32 ? ((const float*)p)[i] : bf(((const __hip_bfloat16*)p)[i]);
}

__device__ __forceinline__ float angf(float ax, float ay, float az,
                                      float bx, float by, float bz) {
  float cx = ay*bz - az*by;
  float cy = az*bx - ax*bz;
  float cz = ax*by - ay*bx;
  float s  = cx*cx + cy*cy + cz*cz;
  float cn = s > 0.f ? sqrtf(s) : 0.f;
  float d  = ax*bx + ay*by + az*bz;
  return (cn > 0.f || d != 0.f) ? atan2f(cn, d) : 0.f;
}

__device__ __forceinline__ void ppf4(const float4 pi, const float4 ni,
                                     const float4 pj, const float4 nj, float* f) {
  float px = pj.x - pi.x, py = pj.y - pi.y, pz = pj.z - pi.z;
  float s = px*px + py*py + pz*pz;
  f[0] = s > 0.f ? sqrtf(s) : 0.f;
  f[1] = angf(ni.x, ni.y, ni.z, px, py, pz);
  f[2] = angf(nj.x, nj.y, nj.z, px, py, pz);
  f[3] = angf(ni.x, ni.y, ni.z, nj.x, nj.y, nj.z);
}

// monotone f32 -> u32 key (order-preserving for all finite floats)
__device__ __forceinline__ unsigned int fkey(float f) {
  unsigned int u = __float_as_uint(f);
  return (u & 0x80000000u) ? ~u : (u | 0x80000000u);
}
__device__ __forceinline__ float funkey(unsigned int k) {
  unsigned int u = (k & 0x80000000u) ? (k ^ 0x80000000u) : ~k;
  return __uint_as_float(u);
}

// ---------------- wprep: parallel dtype vote + weights->fp32 ----------------
__global__ __launch_bounds__(256) void wprep_kernel(
    const void* nrm, const void* w1a, const void* b1a, const void* w1b,
    const void* b1b, const void* w2a, const void* b2a, const void* w2b,
    const void* b2b, const void* wc, const void* bc) {
  __shared__ int sflag;
  const int tid = threadIdx.x;
  if (tid < 64) {
    const float* nf = (const float*)nrm;
    const __hip_bfloat16* nh = (const __hip_bfloat16*)nrm;
    float x = nf[3*tid], y = nf[3*tid+1], z = nf[3*tid+2];
    float ss = x*x + y*y + z*z;
    bool okf = (ss > 0.98f && ss < 1.02f);
    float a = bf(nh[3*tid]), b2 = bf(nh[3*tid+1]), c2 = bf(nh[3*tid+2]);
    float sb = a*a + b2*b2 + c2*c2;
    bool okb = (sb > 0.95f && sb < 1.05f);
    unsigned long long mf = __ballot(okf), mb = __ballot(okb);
    if (tid == 0) {
      sflag = (__popcll(mf) >= __popcll(mb)) ? 1 : 0;
      g_isf32 = sflag;
    }
  }
  __syncthreads();
  const bool f32 = sflag != 0;
  for (int i = tid; i < 128;  i += 256) g_wts[OW1A + i] = ldf(w1a, i, f32);
  for (int i = tid; i < 32;   i += 256) g_wts[OB1A + i] = ldf(b1a, i, f32);
  for (int i = tid; i < 1024; i += 256) g_wts[OW1B + i] = ldf(w1b, i, f32);
  for (int i = tid; i < 32;   i += 256) g_wts[OB1B + i] = ldf(b1b, i, f32);
  for (int i = tid; i < 1152; i += 256) g_wts[OW2A + i] = ldf(w2a, i, f32);
  for (int i = tid; i < 32;   i += 256) g_wts[OB2A + i] = ldf(b2a, i, f32);
  for (int i = tid; i < 1024; i += 256) g_wts[OW2B + i] = ldf(w2b, i, f32);
  for (int i = tid; i < 32;   i += 256) g_wts[OB2B + i] = ldf(b2b, i, f32);
  for (int i = tid; i < 1280; i += 256) g_wts[OWC  + i] = ldf(wc,  i, f32);
  for (int i = tid; i < 40;   i += 256) g_wts[OBC  + i] = ldf(bc,  i, f32);
}

// ---------------- prep: inputs -> float4 (pos.w = |p|^2 f32, filter only) ----------------
__global__ __launch_bounds__(256) void prep_kernel(const void* __restrict__ pos,
                                                   const void* __restrict__ nrm) {
  const bool f32 = g_isf32 != 0;
  int i = blockIdx.x*256 + threadIdx.x;
  float x = ldf(pos, 3*i, f32), y = ldf(pos, 3*i+1, f32), z = ldf(pos, 3*i+2, f32);
  float sq = x*x + y*y + z*z;
  g_pos4[i] = make_float4(x, y, z, sq);
  float a = ldf(nrm, 3*i, f32), b = ldf(nrm, 3*i+1, f32), c = ldf(nrm, 3*i+2, f32);
  g_nrm4[i] = make_float4(a, b, c, 0.f);
}

// ---------------- kNN: 512-thread blocks, SoA xyz tile, interleaved bisection -----------
// Structure validated R12-R17. Filter d2' = |o|^2 - 2*dot(q,o) (|o|^2 recomputed,
// bit-identical both passes; margin covers f32 error). Threshold = exact
// 17th-smallest per-lane column-min via 8 interleaved 32-step ballot bisections
// (self included: self d2' = -|q|^2 is the strict global min => >=16 non-self <= T).
// Pass 2 recomputes + collects into wave-private lists; f64 rescore (numpy-exact
// association) + exact lexicographic (d2_f64, idx) rank. One barrier total.
__global__ __launch_bounds__(512) void knn_kernel() {
  __shared__ float sx[NN], sy[NN], sz[NN];          // 49152 B (SoA xyz tile)
  __shared__ unsigned short ilst[64][CAP];          // 12288 B
  __shared__ double dlst[8][CAP];                   //  6144 B
  __shared__ int    cnt[64];
  const int tid  = threadIdx.x;
  const int w    = tid >> 6, lane = tid & 63;
  const int blk  = blockIdx.x;
  const int b    = blk >> 6;                        // 64 blocks per batch
  const int qbw  = ((blk & 63) << 6) | (w << 3);    // first of this wave's 8 queries
  const float4* bp = g_pos4 + b*NN;

  #pragma unroll
  for (int k = 0; k < 8; ++k) {
    int idx = k*512 + tid;
    float4 o = bp[idx];
    sx[idx] = o.x; sy[idx] = o.y; sz[idx] = o.z;
  }
  __syncthreads();                                  // the only barrier

  float q2x[8], q2y[8], q2z[8];
  #pragma unroll
  for (int qq = 0; qq < 8; ++qq) {
    int qi = qbw + qq;
    q2x[qq] = -2.f*sx[qi]; q2y[qq] = -2.f*sy[qi]; q2z[qq] = -2.f*sz[qi];
  }

  // ---- pass 1: per-lane column mins for 8 queries (self included) ----
  float mn[8];
  #pragma unroll
  for (int qq = 0; qq < 8; ++qq) mn[qq] = BIG;
  #pragma unroll 4
  for (int it = 0; it < 64; ++it) {
    int idx = it*64 + lane;
    float ox = sx[idx], oy = sy[idx], oz = sz[idx];
    float ow = __builtin_fmaf(oz, oz, __builtin_fmaf(oy, oy, ox*ox));
    #pragma unroll
    for (int qq = 0; qq < 8; ++qq) {
      float d = __builtin_fmaf(q2x[qq], ox,
                __builtin_fmaf(q2y[qq], oy,
                __builtin_fmaf(q2z[qq], oz, ow)));
      mn[qq] = fminf(mn[qq], d);
    }
  }

  // ---- threshold: 17th-smallest lane-min, 8 interleaved ballot bisections ----
  unsigned int key[8], lo[8], hi[8];
  #pragma unroll
  for (int qq = 0; qq < 8; ++qq) { key[qq] = fkey(mn[qq]); lo[qq] = 0u; hi[qq] = 0xFFFFFFFFu; }
  #pragma unroll 1
  for (int s = 0; s < 32; ++s) {
    #pragma unroll
    for (int qq = 0; qq < 8; ++qq) {
      unsigned int mid = lo[qq] + ((hi[qq] - lo[qq]) >> 1);
      int c = (int)__popcll(__ballot(key[qq] <= mid));
      if (c >= 17) hi[qq] = mid; else lo[qq] = mid + 1;
    }
  }
  float Tf[8];
  #pragma unroll
  for (int qq = 0; qq < 8; ++qq) {
    float T = funkey(hi[qq]);                       // exact 17th smallest
    Tf[qq] = T + 4e-5f + 1e-5f*fabsf(T);            // margin >> f32 d2' abs error
  }

  if (lane < 8) cnt[(w<<3) | lane] = 0;             // wave-private counters

  // ---- pass 2: recompute + sparse collect into wave-private lists ----
  #pragma unroll 4
  for (int it = 0; it < 64; ++it) {
    int idx = it*64 + lane;
    float ox = sx[idx], oy = sy[idx], oz = sz[idx];
    float ow = __builtin_fmaf(oz, oz, __builtin_fmaf(oy, oy, ox*ox));
    #pragma unroll
    for (int qq = 0; qq < 8; ++qq) {
      float d = __builtin_fmaf(q2x[qq], ox,
                __builtin_fmaf(q2y[qq], oy,
                __builtin_fmaf(q2z[qq], oz, ow)));
      if (d <= Tf[qq] && idx != qbw + qq) {
        int p = atomicAdd(&cnt[(w<<3)|qq], 1);
        if (p < CAP) ilst[(w<<3)|qq][p] = (unsigned short)idx;
      }
    }
  }

  // ---- per query: f64 rescore (numpy-exact, from LDS tile) + exact rank ----
  #pragma unroll 1
  for (int qq = 0; qq < 8; ++qq) {
    const int qi = qbw + qq;
    const int m = min(cnt[(w<<3)|qq], CAP);
    const double mx = (double)sx[qi], my_ = (double)sy[qi], mz = (double)sz[qi];
    const double sqme = (mx*mx + my_*my_) + mz*mz;
    for (int e = lane; e < m; e += 64) {
      int ci = ilst[(w<<3)|qq][e];
      double ox = (double)sx[ci], oy = (double)sy[ci], oz = (double)sz[ci];
      double sqo = (ox*ox + oy*oy) + oz*oz;
      double dt  = (mx*ox + my_*oy) + mz*oz;
      dlst[w][e] = (sqme + sqo) - 2.0*dt;
    }
    for (int e = lane; e < m; e += 64) {
      double myd = dlst[w][e];
      int myi = ilst[(w<<3)|qq][e];
      int rank = 0;
      for (int o = 0; o < m; ++o) {                 // broadcast LDS reads
        double od = dlst[w][o];
        int oi = ilst[(w<<3)|qq][o];
        rank += (od < myd) || (od == myd && oi < myi);
      }
      if (rank < KK) g_nbr[(b*NN + qi)*KK + rank] = b*NN + myi;
    }
  }
}

// ---------------- conv1: 8 nodes/block, fused u = relu(max(msg1)) @ w2a[0:32] ----------------
__global__ __launch_bounds__(256) void conv1_kernel() {
  __shared__ __align__(16) float fe[136][4];
  __shared__ __align__(16) float h1s[8*SLOTS*CH];
  __shared__ __align__(16) float xs[8][CH];
  const int tid = threadIdx.x;
  const int c = tid & 31;
  const int node0 = blockIdx.x << 3;
  float w1a_c[4], w1b_c[32], w2a_c[32];
  #pragma unroll
  for (int f = 0; f < 4; ++f)  w1a_c[f] = g_wts[OW1A + f*CH + c];
  #pragma unroll
  for (int k = 0; k < 32; ++k) w1b_c[k] = g_wts[OW1B + k*CH + c];
  #pragma unroll
  for (int k = 0; k < 32; ++k) w2a_c[k] = g_wts[OW2A + k*CH + c];
  const float b1a_c = g_wts[OB1A + c], b1b_c = g_wts[OB1B + c];

  if (tid < 136) {
    int ns = tid / 17, slot = tid - ns*17;
    int i = node0 + ns;
    int j = (slot < KK) ? g_nbr[i*KK + slot] : i;   // slot 16 = self-loop
    ppf4(g_pos4[i], g_nrm4[i], g_pos4[j], g_nrm4[j], fe[tid]);
  }
  __syncthreads();
  #pragma unroll
  for (int it = 0; it < 17; ++it) {
    int idx = it*256 + tid;                   // (e, c) with c == tid&31
    int e = idx >> 5;
    float4 f4 = *(const float4*)fe[e];
    float h = b1a_c + f4.x*w1a_c[0] + f4.y*w1a_c[1] + f4.z*w1a_c[2] + f4.w*w1a_c[3];
    h1s[idx] = fmaxf(h, 0.f);
  }
  __syncthreads();
  const int ns = tid >> 5;
  const int i  = node0 + ns;
  float acc = -BIG;
  #pragma unroll
  for (int slot = 0; slot < SLOTS; ++slot) {
    const float* hr = &h1s[(ns*SLOTS + slot)*CH];
    float msg = b1b_c;
    #pragma unroll
    for (int k4 = 0; k4 < 8; ++k4) {
      float4 h4 = *(const float4*)(hr + 4*k4);
      msg += h4.x*w1b_c[4*k4] + h4.y*w1b_c[4*k4+1] + h4.z*w1b_c[4*k4+2] + h4.w*w1b_c[4*k4+3];
    }
    acc = fmaxf(acc, msg);
  }
  xs[ns][c] = fmaxf(acc, 0.f);                // x1 = relu(segment_max)
  __syncthreads();
  float uu = 0.f;
  #pragma unroll
  for (int k4 = 0; k4 < 8; ++k4) {
    float4 x4 = *(const float4*)&xs[ns][4*k4];
    uu += x4.x*w2a_c[4*k4] + x4.y*w2a_c[4*k4+1] + x4.z*w2a_c[4*k4+2] + x4.w*w2a_c[4*k4+3];
  }
  g_u[i*CH + c] = uu;                         // u = x1 @ w2a[0:32,:]
}

// ---------------- conv2 (+ block-max epilogue -> g_bmax; x2 never materialized) ---------
__global__ __launch_bounds__(256) void conv2_kernel() {
  __shared__ __align__(16) float fe[136][4];
  __shared__ int jn[136];
  __shared__ __align__(16) float h2s[8*SLOTS*CH];
  __shared__ float xs[8][CH];
  const int tid = threadIdx.x;
  const int c = tid & 31;
  const int node0 = blockIdx.x << 3;
  float w2aL_c[4], w2b_c[32];
  #pragma unroll
  for (int f = 0; f < 4; ++f)  w2aL_c[f] = g_wts[OW2A + (CH + f)*CH + c];
  #pragma unroll
  for (int k = 0; k < 32; ++k) w2b_c[k] = g_wts[OW2B + k*CH + c];
  const float b2a_c = g_wts[OB2A + c], b2b_c = g_wts[OB2B + c];

  if (tid < 136) {
    int ns = tid / 17, slot = tid - ns*17;
    int i = node0 + ns;
    int j = (slot < KK) ? g_nbr[i*KK + slot] : i;
    jn[tid] = j;
    ppf4(g_pos4[i], g_nrm4[i], g_pos4[j], g_nrm4[j], fe[tid]);
  }
  __syncthreads();
  #pragma unroll
  for (int it = 0; it < 17; ++it) {
    int idx = it*256 + tid;
    int e = idx >> 5;
    float4 f4 = *(const float4*)fe[e];
    float uv = g_u[jn[e]*CH + c];             // x_j @ w2a[0:32] precomputed
    float h = b2a_c + uv + f4.x*w2aL_c[0] + f4.y*w2aL_c[1] + f4.z*w2aL_c[2] + f4.w*w2aL_c[3];
    h2s[idx] = fmaxf(h, 0.f);
  }
  __syncthreads();
  const int ns = tid >> 5;
  float acc = -BIG;
  #pragma unroll
  for (int slot = 0; slot < SLOTS; ++slot) {
    const float* hr = &h2s[(ns*SLOTS + slot)*CH];
    float msg = b2b_c;
    #pragma unroll
    for (int k4 = 0; k4 < 8; ++k4) {
      float4 h4 = *(const float4*)(hr + 4*k4);
      msg += h4.x*w2b_c[4*k4] + h4.y*w2b_c[4*k4+1] + h4.z*w2b_c[4*k4+2] + h4.w*w2b_c[4*k4+3];
    }
    acc = fmaxf(acc, msg);
  }
  xs[ns][c] = fmaxf(acc, 0.f);                // x2 = relu(segment_max)
  __syncthreads();
  if (tid < CH) {                             // block max -> plain coalesced store
    float m2 = xs[0][c];
    #pragma unroll
    for (int r = 1; r < 8; ++r) m2 = fmaxf(m2, xs[r][c]);
    g_bmax[blockIdx.x*CH + c] = m2;           // no atomics (R17's atomicMax on
  }                                           // 2 cache lines/graph serialized)
}

// ---------------- head: two-stage max over g_bmax + 32->40 matmul (f32 out) -------------
__global__ __launch_bounds__(256) void head_kernel(float* __restrict__ out) {
  __shared__ float red[8][CH];
  __shared__ float gm[CH];
  const int g = blockIdx.x;
  const int c = threadIdx.x & 31, sub = threadIdx.x >> 5;
  const float* base = g_bmax + (size_t)(g*512 + sub*64)*CH;   // 512 conv2 blocks/graph
  float mx = 0.f;                                             // x2 >= 0 (relu)
  #pragma unroll
  for (int n = 0; n < 64; ++n) mx = fmaxf(mx, base[n*CH + c]);
  red[sub][c] = mx;
  __syncthreads();
  if (threadIdx.x < CH) {
    float m2 = red[0][c];
    #pragma unroll
    for (int r = 1; r < 8; ++r) m2 = fmaxf(m2, red[r][c]);
    gm[c] = m2;
  }
  __syncthreads();
  if (threadIdx.x < NCLS) {
    int co = threadIdx.x;
    float s = g_wts[OBC + co];
    #pragma unroll
    for (int f = 0; f < CH; ++f) s += gm[f] * g_wts[OWC + f*NCLS + co];
    out[g*NCLS + co] = s;                     // float32 out (reference dtype)
  }
}

extern "C" void kernel_launch(void* const* d_in, const int* in_sizes, int n_in,
                              void* d_out, int out_size, void* d_ws, size_t ws_size,
                              hipStream_t stream) {
  const void* pos = d_in[0];
  const void* nrm = d_in[1];
  // d_in[2] = batch (int32) -- unused, batches are uniform
  const void* w1a = d_in[3];
  const void* b1a = d_in[4];
  const void* w1b = d_in[5];
  const void* b1b = d_in[6];
  const void* w2a = d_in[7];
  const void* b2a = d_in[8];
  const void* w2b = d_in[9];
  const void* b2b = d_in[10];
  const void* wc  = d_in[11];
  const void* bc  = d_in[12];

  wprep_kernel<<<1,      256, 0, stream>>>(nrm, w1a, b1a, w1b, b1b, w2a, b2a, w2b, b2b, wc, bc);
  prep_kernel <<<MM/256, 256, 0, stream>>>(pos, nrm);
  knn_kernel  <<<MM/64,  512, 0, stream>>>();
  conv1_kernel<<<MM/8,   256, 0, stream>>>();
  conv2_kernel<<<MM/8,   256, 0, stream>>>();
  head_kernel <<<NB,     256, 0, stream>>>((float*)d_out);
}

// Round 19
// 227.007 us; speedup vs baseline: 1.1038x; 1.0058x over previous
//
#include <hip/hip_runtime.h>
#include <hip/hip_bf16.h>
#include <math.h>

#define NB 8
#define NN 4096
#define KK 16
#define MM (NB*NN)
#define CH 32
#define SLOTS 17
#define NCLS 40
#define BIG 3.0e38f
#define CAP 96    // survivors ~20-25 with 17th-lane-min threshold (validated R12-R18)
#define NBLK2 (MM/8)   // conv2 block count (8 nodes/block)
#define AROW 40        // padded LDS row stride (shorts): 80B -> 16B-aligned, 2-way banks

// Weight table offsets (floats)
#define OW1A 0
#define OB1A 128
#define OW1B 160
#define OB1B 1184
#define OW2A 1216
#define OB2A 2368
#define OW2B 2400
#define OB2B 3424
#define OWC  3456
#define OBC  4736
#define NWTS 4776

typedef short short8 __attribute__((ext_vector_type(8)));
typedef float f32x4  __attribute__((ext_vector_type(4)));

// Module-global scratch (~12 MB): no assumptions about ws_size.
__device__ float4 g_pos4[MM];
__device__ float4 g_nrm4[MM];
__device__ int    g_nbr[MM*KK];
__device__ float  g_u[MM*CH];
__device__ float  g_bmax[NBLK2*CH];   // per-conv2-block channel maxima (no atomics)
__device__ float  g_wts[NWTS];
// Pre-split (bf16 hi/lo) + pre-swizzled B-fragments for 16x16x32 MFMA:
// [ntile][hi/lo][lane][j] with value = W[k=(lane>>4)*8+j][n=ntile*16+(lane&15)]
__device__ __align__(16) unsigned short g_wfrag1[2][2][64][8];
__device__ __align__(16) unsigned short g_wfrag2[2][2][64][8];
__device__ int    g_isf32;

__device__ __forceinline__ float bf(const __hip_bfloat16 x) { return __bfloat162float(x); }

__device__ __forceinline__ float ldf(const void* p, int i, bool f32) {
  return f32 ? ((const float*)p)[i] : bf(((const __hip_bfloat16*)p)[i]);
}

__device__ __forceinline__ float angf(float ax, float ay, float az,
                                      float bx, float by, float bz) {
  float cx = ay*bz - az*by;
  float cy = az*bx - ax*bz;
  float cz = ax*by - ay*bx;
  float s  = cx*cx + cy*cy + cz*cz;
  float cn = s > 0.f ? sqrtf(s) : 0.f;
  float d  = ax*bx + ay*by + az*bz;
  return (cn > 0.f || d != 0.f) ? atan2f(cn, d) : 0.f;
}

__device__ __forceinline__ void ppf4(const float4 pi, const float4 ni,
                                     const float4 pj, const float4 nj, float* f) {
  float px = pj.x - pi.x, py = pj.y - pi.y, pz = pj.z - pi.z;
  float s = px*px + py*py + pz*pz;
  f[0] = s > 0.f ? sqrtf(s) : 0.f;
  f[1] = angf(ni.x, ni.y, ni.z, px, py, pz);
  f[2] = angf(nj.x, nj.y, nj.z, px, py, pz);
  f[3] = angf(ni.x, ni.y, ni.z, nj.x, nj.y, nj.z);
}

// monotone f32 -> u32 key (order-preserving for all finite floats)
__device__ __forceinline__ unsigned int fkey(float f) {
  unsigned int u = __float_as_uint(f);
  return (u & 0x80000000u) ? ~u : (u | 0x80000000u);
}
__device__ __forceinline__ float funkey(unsigned int k) {
  unsigned int u = (k & 0x80000000u) ? (k ^ 0x80000000u) : ~k;
  return __uint_as_float(u);
}

// split f32 -> bf16 hi/lo bit patterns
__device__ __forceinline__ void bsplit(float v, unsigned short* hi, unsigned short* lo) {
  __hip_bfloat16 h = __float2bfloat16(v);
  float hf = __bfloat162float(h);
  __hip_bfloat16 l = __float2bfloat16(v - hf);
  *hi = *reinterpret_cast<unsigned short*>(&h);
  *lo = *reinterpret_cast<unsigned short*>(&l);
}

// ---------------- wprep: dtype vote + weights->fp32 + MFMA B-fragment tables ------------
__global__ __launch_bounds__(256) void wprep_kernel(
    const void* nrm, const void* w1a, const void* b1a, const void* w1b,
    const void* b1b, const void* w2a, const void* b2a, const void* w2b,
    const void* b2b, const void* wc, const void* bc) {
  __shared__ int sflag;
  const int tid = threadIdx.x;
  if (tid < 64) {
    const float* nf = (const float*)nrm;
    const __hip_bfloat16* nh = (const __hip_bfloat16*)nrm;
    float x = nf[3*tid], y = nf[3*tid+1], z = nf[3*tid+2];
    float ss = x*x + y*y + z*z;
    bool okf = (ss > 0.98f && ss < 1.02f);
    float a = bf(nh[3*tid]), b2 = bf(nh[3*tid+1]), c2 = bf(nh[3*tid+2]);
    float sb = a*a + b2*b2 + c2*c2;
    bool okb = (sb > 0.95f && sb < 1.05f);
    unsigned long long mf = __ballot(okf), mb = __ballot(okb);
    if (tid == 0) {
      sflag = (__popcll(mf) >= __popcll(mb)) ? 1 : 0;
      g_isf32 = sflag;
    }
  }
  __syncthreads();
  const bool f32 = sflag != 0;
  for (int i = tid; i < 128;  i += 256) g_wts[OW1A + i] = ldf(w1a, i, f32);
  for (int i = tid; i < 32;   i += 256) g_wts[OB1A + i] = ldf(b1a, i, f32);
  for (int i = tid; i < 1024; i += 256) g_wts[OW1B + i] = ldf(w1b, i, f32);
  for (int i = tid; i < 32;   i += 256) g_wts[OB1B + i] = ldf(b1b, i, f32);
  for (int i = tid; i < 1152; i += 256) g_wts[OW2A + i] = ldf(w2a, i, f32);
  for (int i = tid; i < 32;   i += 256) g_wts[OB2A + i] = ldf(b2a, i, f32);
  for (int i = tid; i < 1024; i += 256) g_wts[OW2B + i] = ldf(w2b, i, f32);
  for (int i = tid; i < 32;   i += 256) g_wts[OB2B + i] = ldf(b2b, i, f32);
  for (int i = tid; i < 1280; i += 256) g_wts[OWC  + i] = ldf(wc,  i, f32);
  for (int i = tid; i < 40;   i += 256) g_wts[OBC  + i] = ldf(bc,  i, f32);
  // B-fragment tables (from raw inputs; independent of g_wts writes above)
  for (int i = tid; i < 4096; i += 256) {
    int which = i >> 11;                 // 0 = w1b, 1 = w2b
    int r = i & 2047;
    int t  = r >> 10;  r &= 1023;
    int hl = r >> 9;   r &= 511;
    int ln = r >> 3;
    int j  = r & 7;
    int k = (ln >> 4)*8 + j;
    int c = t*16 + (ln & 15);
    float wv = ldf(which ? w2b : w1b, k*CH + c, f32);
    unsigned short hi, lo;
    bsplit(wv, &hi, &lo);
    unsigned short v = hl ? lo : hi;
    if (which) g_wfrag2[t][hl][ln][j] = v;
    else       g_wfrag1[t][hl][ln][j] = v;
  }
}

// ---------------- prep: inputs -> float4 (pos.w = |p|^2 f32, filter only) ----------------
__global__ __launch_bounds__(256) void prep_kernel(const void* __restrict__ pos,
                                                   const void* __restrict__ nrm) {
  const bool f32 = g_isf32 != 0;
  int i = blockIdx.x*256 + threadIdx.x;
  float x = ldf(pos, 3*i, f32), y = ldf(pos, 3*i+1, f32), z = ldf(pos, 3*i+2, f32);
  float sq = x*x + y*y + z*z;
  g_pos4[i] = make_float4(x, y, z, sq);
  float a = ldf(nrm, 3*i, f32), b = ldf(nrm, 3*i+1, f32), c = ldf(nrm, 3*i+2, f32);
  g_nrm4[i] = make_float4(a, b, c, 0.f);
}

// ---------------- kNN: 512-thread blocks, SoA xyz tile, interleaved bisection -----------
// Structure validated R12-R18 (see prior rounds' comments).
__global__ __launch_bounds__(512) void knn_kernel() {
  __shared__ float sx[NN], sy[NN], sz[NN];          // 49152 B (SoA xyz tile)
  __shared__ unsigned short ilst[64][CAP];          // 12288 B
  __shared__ double dlst[8][CAP];                   //  6144 B
  __shared__ int    cnt[64];
  const int tid  = threadIdx.x;
  const int w    = tid >> 6, lane = tid & 63;
  const int blk  = blockIdx.x;
  const int b    = blk >> 6;                        // 64 blocks per batch
  const int qbw  = ((blk & 63) << 6) | (w << 3);    // first of this wave's 8 queries
  const float4* bp = g_pos4 + b*NN;

  #pragma unroll
  for (int k = 0; k < 8; ++k) {
    int idx = k*512 + tid;
    float4 o = bp[idx];
    sx[idx] = o.x; sy[idx] = o.y; sz[idx] = o.z;
  }
  __syncthreads();                                  // the only barrier

  float q2x[8], q2y[8], q2z[8];
  #pragma unroll
  for (int qq = 0; qq < 8; ++qq) {
    int qi = qbw + qq;
    q2x[qq] = -2.f*sx[qi]; q2y[qq] = -2.f*sy[qi]; q2z[qq] = -2.f*sz[qi];
  }

  float mn[8];
  #pragma unroll
  for (int qq = 0; qq < 8; ++qq) mn[qq] = BIG;
  #pragma unroll 4
  for (int it = 0; it < 64; ++it) {
    int idx = it*64 + lane;
    float ox = sx[idx], oy = sy[idx], oz = sz[idx];
    float ow = __builtin_fmaf(oz, oz, __builtin_fmaf(oy, oy, ox*ox));
    #pragma unroll
    for (int qq = 0; qq < 8; ++qq) {
      float d = __builtin_fmaf(q2x[qq], ox,
                __builtin_fmaf(q2y[qq], oy,
                __builtin_fmaf(q2z[qq], oz, ow)));
      mn[qq] = fminf(mn[qq], d);
    }
  }

  unsigned int key[8], lo[8], hi[8];
  #pragma unroll
  for (int qq = 0; qq < 8; ++qq) { key[qq] = fkey(mn[qq]); lo[qq] = 0u; hi[qq] = 0xFFFFFFFFu; }
  #pragma unroll 1
  for (int s = 0; s < 32; ++s) {
    #pragma unroll
    for (int qq = 0; qq < 8; ++qq) {
      unsigned int mid = lo[qq] + ((hi[qq] - lo[qq]) >> 1);
      int c = (int)__popcll(__ballot(key[qq] <= mid));
      if (c >= 17) hi[qq] = mid; else lo[qq] = mid + 1;
    }
  }
  float Tf[8];
  #pragma unroll
  for (int qq = 0; qq < 8; ++qq) {
    float T = funkey(hi[qq]);                       // exact 17th smallest
    Tf[qq] = T + 4e-5f + 1e-5f*fabsf(T);            // margin >> f32 d2' abs error
  }

  if (lane < 8) cnt[(w<<3) | lane] = 0;             // wave-private counters

  #pragma unroll 4
  for (int it = 0; it < 64; ++it) {
    int idx = it*64 + lane;
    float ox = sx[idx], oy = sy[idx], oz = sz[idx];
    float ow = __builtin_fmaf(oz, oz, __builtin_fmaf(oy, oy, ox*ox));
    #pragma unroll
    for (int qq = 0; qq < 8; ++qq) {
      float d = __builtin_fmaf(q2x[qq], ox,
                __builtin_fmaf(q2y[qq], oy,
                __builtin_fmaf(q2z[qq], oz, ow)));
      if (d <= Tf[qq] && idx != qbw + qq) {
        int p = atomicAdd(&cnt[(w<<3)|qq], 1);
        if (p < CAP) ilst[(w<<3)|qq][p] = (unsigned short)idx;
      }
    }
  }

  #pragma unroll 1
  for (int qq = 0; qq < 8; ++qq) {
    const int qi = qbw + qq;
    const int m = min(cnt[(w<<3)|qq], CAP);
    const double mx = (double)sx[qi], my_ = (double)sy[qi], mz = (double)sz[qi];
    const double sqme = (mx*mx + my_*my_) + mz*mz;
    for (int e = lane; e < m; e += 64) {
      int ci = ilst[(w<<3)|qq][e];
      double ox = (double)sx[ci], oy = (double)sy[ci], oz = (double)sz[ci];
      double sqo = (ox*ox + oy*oy) + oz*oz;
      double dt  = (mx*ox + my_*oy) + mz*oz;
      dlst[w][e] = (sqme + sqo) - 2.0*dt;
    }
    for (int e = lane; e < m; e += 64) {
      double myd = dlst[w][e];
      int myi = ilst[(w<<3)|qq][e];
      int rank = 0;
      for (int o = 0; o < m; ++o) {                 // broadcast LDS reads
        double od = dlst[w][o];
        int oi = ilst[(w<<3)|qq][o];
        rank += (od < myd) || (od == myd && oi < myi);
      }
      if (rank < KK) g_nbr[(b*NN + qi)*KK + rank] = b*NN + myi;
    }
  }
}

// ---------------- conv1: MFMA (split-bf16) second layer, fused u epilogue ---------------
// h (136x32, padded to 8 nodes x 32 slot-rows) @ w1b (32x32) via 16x16x32 bf16 MFMA,
// 3-term split (hi*hi + hi*lo + lo*hi; lo*lo ~ 2^-16 rel, negligible vs 2% tol).
// A-layout: lane holds A[m=lane&15][k=(lane>>4)*8+j] (verified m120); C/D: col=lane&15,
// row=(lane>>4)*4+reg (verified m89/m91). Pad rows masked with -BIG before the max
// (MFMA rows are independent, garbage stays in its row). Bias added after max.
__global__ __launch_bounds__(256) void conv1_kernel() {
  __shared__ __align__(16) float fe[136][4];
  __shared__ __align__(16) short aHi[256*AROW];   // 20480 B
  __shared__ __align__(16) short aLo[256*AROW];   // 20480 B
  __shared__ __align__(16) float xs[8][CH];
  const int tid = threadIdx.x;
  const int c = tid & 31;
  const int lane = tid & 63, wv = tid >> 6;
  const int quad = lane >> 4, l15 = lane & 15;
  const int node0 = blockIdx.x << 3;
  float w1a_c[4], w2a_c[32];
  #pragma unroll
  for (int f = 0; f < 4; ++f)  w1a_c[f] = g_wts[OW1A + f*CH + c];
  #pragma unroll
  for (int k = 0; k < 32; ++k) w2a_c[k] = g_wts[OW2A + k*CH + c];
  const float b1a_c = g_wts[OB1A + c];
  // B-fragments (register-resident, shared by all MFMAs)
  short8 bH0 = *(const short8*)&g_wfrag1[0][0][lane][0];
  short8 bL0 = *(const short8*)&g_wfrag1[0][1][lane][0];
  short8 bH1 = *(const short8*)&g_wfrag1[1][0][lane][0];
  short8 bL1 = *(const short8*)&g_wfrag1[1][1][lane][0];
  const float bias0 = g_wts[OB1B + l15];        // col bias for ntile 0
  const float bias1 = g_wts[OB1B + 16 + l15];   // col bias for ntile 1

  if (tid < 136) {
    int ns = tid / 17, slot = tid - ns*17;
    int i = node0 + ns;
    int j = (slot < KK) ? g_nbr[i*KK + slot] : i;   // slot 16 = self-loop
    ppf4(g_pos4[i], g_nrm4[i], g_pos4[j], g_nrm4[j], fe[tid]);
  }
  __syncthreads();
  // h-phase: h = relu(b1a + fe.w1a), split to bf16 hi/lo in A-layout rows
  #pragma unroll
  for (int it = 0; it < 17; ++it) {
    int idx = it*256 + tid;
    int e = idx >> 5;                         // c == tid&31
    int nd = e / 17, slot = e - nd*17;
    float4 f4 = *(const float4*)fe[e];
    float h = b1a_c + f4.x*w1a_c[0] + f4.y*w1a_c[1] + f4.z*w1a_c[2] + f4.w*w1a_c[3];
    h = fmaxf(h, 0.f);
    unsigned short hb, lb;
    bsplit(h, &hb, &lb);
    int row = nd*32 + slot;
    aHi[row*AROW + c] = (short)hb;
    aLo[row*AROW + c] = (short)lb;
  }
  __syncthreads();
  // MFMA phase: each wave handles 2 nodes
  #pragma unroll
  for (int ni = 0; ni < 2; ++ni) {
    const int n8 = wv*2 + ni;
    const int rbase = n8*32;
    short8 ah0 = *(const short8*)&aHi[(rbase      + l15)*AROW + quad*8];
    short8 al0 = *(const short8*)&aLo[(rbase      + l15)*AROW + quad*8];
    short8 ah1 = *(const short8*)&aHi[(rbase + 16 + l15)*AROW + quad*8];
    short8 al1 = *(const short8*)&aLo[(rbase + 16 + l15)*AROW + quad*8];
    f32x4 a00 = {0.f,0.f,0.f,0.f}, a01 = a00, a10 = a00, a11 = a00;
    a00 = __builtin_amdgcn_mfma_f32_16x16x32_bf16(ah0, bH0, a00, 0, 0, 0);
    a00 = __builtin_amdgcn_mfma_f32_16x16x32_bf16(ah0, bL0, a00, 0, 0, 0);
    a00 = __builtin_amdgcn_mfma_f32_16x16x32_bf16(al0, bH0, a00, 0, 0, 0);
    a01 = __builtin_amdgcn_mfma_f32_16x16x32_bf16(ah0, bH1, a01, 0, 0, 0);
    a01 = __builtin_amdgcn_mfma_f32_16x16x32_bf16(ah0, bL1, a01, 0, 0, 0);
    a01 = __builtin_amdgcn_mfma_f32_16x16x32_bf16(al0, bH1, a01, 0, 0, 0);
    a10 = __builtin_amdgcn_mfma_f32_16x16x32_bf16(ah1, bH0, a10, 0, 0, 0);
    a10 = __builtin_amdgcn_mfma_f32_16x16x32_bf16(ah1, bL0, a10, 0, 0, 0);
    a10 = __builtin_amdgcn_mfma_f32_16x16x32_bf16(al1, bH0, a10, 0, 0, 0);
    a11 = __builtin_amdgcn_mfma_f32_16x16x32_bf16(ah1, bH1, a11, 0, 0, 0);
    a11 = __builtin_amdgcn_mfma_f32_16x16x32_bf16(ah1, bL1, a11, 0, 0, 0);
    a11 = __builtin_amdgcn_mfma_f32_16x16x32_bf16(al1, bH1, a11, 0, 0, 0);
    // segment max: tile0 rows = slots quad*4+reg (all < 17); tile1 only slot 16 (quad0,reg0)
    float m0 = fmaxf(fmaxf(a00[0], a00[1]), fmaxf(a00[2], a00[3]));
    float m1 = fmaxf(fmaxf(a01[0], a01[1]), fmaxf(a01[2], a01[3]));
    if (quad == 0) { m0 = fmaxf(m0, a10[0]); m1 = fmaxf(m1, a11[0]); }
    m0 = fmaxf(m0, __shfl_xor(m0, 16)); m0 = fmaxf(m0, __shfl_xor(m0, 32));
    m1 = fmaxf(m1, __shfl_xor(m1, 16)); m1 = fmaxf(m1, __shfl_xor(m1, 32));
    if (quad == 0) {
      xs[n8][l15]      = fmaxf(m0 + bias0, 0.f);    // x1 = relu(max + b1b)
      xs[n8][16 + l15] = fmaxf(m1 + bias1, 0.f);
    }
  }
  __syncthreads();
  const int ns = tid >> 5;
  float uu = 0.f;
  #pragma unroll
  for (int k4 = 0; k4 < 8; ++k4) {
    float4 x4 = *(const float4*)&xs[ns][4*k4];
    uu += x4.x*w2a_c[4*k4] + x4.y*w2a_c[4*k4+1] + x4.z*w2a_c[4*k4+2] + x4.w*w2a_c[4*k4+3];
  }
  g_u[(node0 + ns)*CH + c] = uu;              // u = x1 @ w2a[0:32,:]
}

// ---------------- conv2: MFMA (split-bf16) second layer + block-max -> g_bmax -----------
__global__ __launch_bounds__(256) void conv2_kernel() {
  __shared__ __align__(16) float fe[136][4];
  __shared__ int jn[136];
  __shared__ __align__(16) short aHi[256*AROW];
  __shared__ __align__(16) short aLo[256*AROW];
  __shared__ __align__(16) float xs[8][CH];
  const int tid = threadIdx.x;
  const int c = tid & 31;
  const int lane = tid & 63, wv = tid >> 6;
  const int quad = lane >> 4, l15 = lane & 15;
  const int node0 = blockIdx.x << 3;
  float w2aL_c[4];
  #pragma unroll
  for (int f = 0; f < 4; ++f)  w2aL_c[f] = g_wts[OW2A + (CH + f)*CH + c];
  const float b2a_c = g_wts[OB2A + c];
  short8 bH0 = *(const short8*)&g_wfrag2[0][0][lane][0];
  short8 bL0 = *(const short8*)&g_wfrag2[0][1][lane][0];
  short8 bH1 = *(const short8*)&g_wfrag2[1][0][lane][0];
  short8 bL1 = *(const short8*)&g_wfrag2[1][1][lane][0];
  const float bias0 = g_wts[OB2B + l15];
  const float bias1 = g_wts[OB2B + 16 + l15];

  if (tid < 136) {
    int ns = tid / 17, slot = tid - ns*17;
    int i = node0 + ns;
    int j = (slot < KK) ? g_nbr[i*KK + slot] : i;
    jn[tid] = j;
    ppf4(g_pos4[i], g_nrm4[i], g_pos4[j], g_nrm4[j], fe[tid]);
  }
  __syncthreads();
  #pragma unroll
  for (int it = 0; it < 17; ++it) {
    int idx = it*256 + tid;
    int e = idx >> 5;
    int nd = e / 17, slot = e - nd*17;
    float4 f4 = *(const float4*)fe[e];
    float uv = g_u[jn[e]*CH + c];             // x_j @ w2a[0:32] precomputed
    float h = b2a_c + uv + f4.x*w2aL_c[0] + f4.y*w2aL_c[1] + f4.z*w2aL_c[2] + f4.w*w2aL_c[3];
    h = fmaxf(h, 0.f);
    unsigned short hb, lb;
    bsplit(h, &hb, &lb);
    int row = nd*32 + slot;
    aHi[row*AROW + c] = (short)hb;
    aLo[row*AROW + c] = (short)lb;
  }
  __syncthreads();
  #pragma unroll
  for (int ni = 0; ni < 2; ++ni) {
    const int n8 = wv*2 + ni;
    const int rbase = n8*32;
    short8 ah0 = *(const short8*)&aHi[(rbase      + l15)*AROW + quad*8];
    short8 al0 = *(const short8*)&aLo[(rbase      + l15)*AROW + quad*8];
    short8 ah1 = *(const short8*)&aHi[(rbase + 16 + l15)*AROW + quad*8];
    short8 al1 = *(const short8*)&aLo[(rbase + 16 + l15)*AROW + quad*8];
    f32x4 a00 = {0.f,0.f,0.f,0.f}, a01 = a00, a10 = a00, a11 = a00;
    a00 = __builtin_amdgcn_mfma_f32_16x16x32_bf16(ah0, bH0, a00, 0, 0, 0);
    a00 = __builtin_amdgcn_mfma_f32_16x16x32_bf16(ah0, bL0, a00, 0, 0, 0);
    a00 = __builtin_amdgcn_mfma_f32_16x16x32_bf16(al0, bH0, a00, 0, 0, 0);
    a01 = __builtin_amdgcn_mfma_f32_16x16x32_bf16(ah0, bH1, a01, 0, 0, 0);
    a01 = __builtin_amdgcn_mfma_f32_16x16x32_bf16(ah0, bL1, a01, 0, 0, 0);
    a01 = __builtin_amdgcn_mfma_f32_16x16x32_bf16(al0, bH1, a01, 0, 0, 0);
    a10 = __builtin_amdgcn_mfma_f32_16x16x32_bf16(ah1, bH0, a10, 0, 0, 0);
    a10 = __builtin_amdgcn_mfma_f32_16x16x32_bf16(ah1, bL0, a10, 0, 0, 0);
    a10 = __builtin_amdgcn_mfma_f32_16x16x32_bf16(al1, bH0, a10, 0, 0, 0);
    a11 = __builtin_amdgcn_mfma_f32_16x16x32_bf16(ah1, bH1, a11, 0, 0, 0);
    a11 = __builtin_amdgcn_mfma_f32_16x16x32_bf16(ah1, bL1, a11, 0, 0, 0);
    a11 = __builtin_amdgcn_mfma_f32_16x16x32_bf16(al1, bH1, a11, 0, 0, 0);
    float m0 = fmaxf(fmaxf(a00[0], a00[1]), fmaxf(a00[2], a00[3]));
    float m1 = fmaxf(fmaxf(a01[0], a01[1]), fmaxf(a01[2], a01[3]));
    if (quad == 0) { m0 = fmaxf(m0, a10[0]); m1 = fmaxf(m1, a11[0]); }
    m0 = fmaxf(m0, __shfl_xor(m0, 16)); m0 = fmaxf(m0, __shfl_xor(m0, 32));
    m1 = fmaxf(m1, __shfl_xor(m1, 16)); m1 = fmaxf(m1, __shfl_xor(m1, 32));
    if (quad == 0) {
      xs[n8][l15]      = fmaxf(m0 + bias0, 0.f);    // x2 = relu(max + b2b)
      xs[n8][16 + l15] = fmaxf(m1 + bias1, 0.f);
    }
  }
  __syncthreads();
  if (tid < CH) {                             // block max -> plain coalesced store
    float m2 = xs[0][c];
    #pragma unroll
    for (int r = 1; r < 8; ++r) m2 = fmaxf(m2, xs[r][c]);
    g_bmax[blockIdx.x*CH + c] = m2;
  }
}

// ---------------- head: two-stage max over g_bmax + 32->40 matmul (f32 out) -------------
__global__ __launch_bounds__(256) void head_kernel(float* __restrict__ out) {
  __shared__ float red[8][CH];
  __shared__ float gm[CH];
  const int g = blockIdx.x;
  const int c = threadIdx.x & 31, sub = threadIdx.x >> 5;
  const float* base = g_bmax + (size_t)(g*512 + sub*64)*CH;   // 512 conv2 blocks/graph
  float mx = 0.f;                                             // x2 >= 0 (relu)
  #pragma unroll
  for (int n = 0; n < 64; ++n) mx = fmaxf(mx, base[n*CH + c]);
  red[sub][c] = mx;
  __syncthreads();
  if (threadIdx.x < CH) {
    float m2 = red[0][c];
    #pragma unroll
    for (int r = 1; r < 8; ++r) m2 = fmaxf(m2, red[r][c]);
    gm[c] = m2;
  }
  __syncthreads();
  if (threadIdx.x < NCLS) {
    int co = threadIdx.x;
    float s = g_wts[OBC + co];
    #pragma unroll
    for (int f = 0; f < CH; ++f) s += gm[f] * g_wts[OWC + f*NCLS + co];
    out[g*NCLS + co] = s;                     // float32 out (reference dtype)
  }
}

extern "C" void kernel_launch(void* const* d_in, const int* in_sizes, int n_in,
                              void* d_out, int out_size, void* d_ws, size_t ws_size,
                              hipStream_t stream) {
  const void* pos = d_in[0];
  const void* nrm = d_in[1];
  // d_in[2] = batch (int32) -- unused, batches are uniform
  const void* w1a = d_in[3];
  const void* b1a = d_in[4];
  const void* w1b = d_in[5];
  const void* b1b = d_in[6];
  const void* w2a = d_in[7];
  const void* b2a = d_in[8];
  const void* w2b = d_in[9];
  const void* b2b = d_in[10];
  const void* wc  = d_in[11];
  const void* bc  = d_in[12];

  wprep_kernel<<<1,      256, 0, stream>>>(nrm, w1a, b1a, w1b, b1b, w2a, b2a, w2b, b2b, wc, bc);
  prep_kernel <<<MM/256, 256, 0, stream>>>(pos, nrm);
  knn_kernel  <<<MM/64,  512, 0, stream>>>();
  conv1_kernel<<<MM/8,   256, 0, stream>>>();
  conv2_kernel<<<MM/8,   256, 0, stream>>>();
  head_kernel <<<NB,     256, 0, stream>>>((float*)d_out);
}

// Round 20
// 213.981 us; speedup vs baseline: 1.1710x; 1.0609x over previous
//
#include <hip/hip_runtime.h>
#include <hip/hip_bf16.h>
#include <math.h>

#define NB 8
#define NN 4096
#define KK 16
#define MM (NB*NN)
#define CH 32
#define SLOTS 17
#define NCLS 40
#define BIG 3.0e38f
#define CAP 96    // survivors ~20-25 with 17th-lane-min threshold (validated R12-R19)
#define NBLK2 (MM/8)   // conv2 block count (8 nodes/block)
#define HROW 36        // h1s row stride (f32): 144B -> 16B-aligned, 2-way banks (free)

// Weight table offsets (floats)
#define OW1A 0
#define OB1A 128
#define OW1B 160
#define OB1B 1184
#define OW2A 1216
#define OB2A 2368
#define OW2B 2400
#define OB2B 3424
#define OWC  3456
#define OBC  4736
#define NWTS 4776

typedef short short8 __attribute__((ext_vector_type(8)));
typedef float f32x4  __attribute__((ext_vector_type(4)));

// Module-global scratch (~12 MB): no assumptions about ws_size.
__device__ float4 g_pos4[MM];
__device__ float4 g_nrm4[MM];
__device__ int    g_nbr[MM*KK];
__device__ float  g_u[MM*CH];
__device__ float  g_bmax[NBLK2*CH];   // per-conv2-block channel maxima (no atomics)
__device__ float  g_wts[NWTS];
// Pre-split (bf16 hi/lo) + pre-swizzled B-fragments for 16x16x32 MFMA:
// [ntile][hi/lo][lane][j] with value = W[k=(lane>>4)*8+j][n=ntile*16+(lane&15)]
__device__ __align__(16) unsigned short g_wfrag1[2][2][64][8];
__device__ __align__(16) unsigned short g_wfrag2[2][2][64][8];
__device__ int    g_isf32;

__device__ __forceinline__ float bf(const __hip_bfloat16 x) { return __bfloat162float(x); }

__device__ __forceinline__ float ldf(const void* p, int i, bool f32) {
  return f32 ? ((const float*)p)[i] : bf(((const __hip_bfloat16*)p)[i]);
}

__device__ __forceinline__ float angf(float ax, float ay, float az,
                                      float bx, float by, float bz) {
  float cx = ay*bz - az*by;
  float cy = az*bx - ax*bz;
  float cz = ax*by - ay*bx;
  float s  = cx*cx + cy*cy + cz*cz;
  float cn = s > 0.f ? sqrtf(s) : 0.f;
  float d  = ax*bx + ay*by + az*bz;
  return (cn > 0.f || d != 0.f) ? atan2f(cn, d) : 0.f;
}

__device__ __forceinline__ void ppf4(const float4 pi, const float4 ni,
                                     const float4 pj, const float4 nj, float* f) {
  float px = pj.x - pi.x, py = pj.y - pi.y, pz = pj.z - pi.z;
  float s = px*px + py*py + pz*pz;
  f[0] = s > 0.f ? sqrtf(s) : 0.f;
  f[1] = angf(ni.x, ni.y, ni.z, px, py, pz);
  f[2] = angf(nj.x, nj.y, nj.z, px, py, pz);
  f[3] = angf(ni.x, ni.y, ni.z, nj.x, nj.y, nj.z);
}

// monotone f32 -> u32 key (order-preserving for all finite floats)
__device__ __forceinline__ unsigned int fkey(float f) {
  unsigned int u = __float_as_uint(f);
  return (u & 0x80000000u) ? ~u : (u | 0x80000000u);
}
__device__ __forceinline__ float funkey(unsigned int k) {
  unsigned int u = (k & 0x80000000u) ? (k ^ 0x80000000u) : ~k;
  return __uint_as_float(u);
}

// split f32 -> bf16 hi/lo bit patterns
__device__ __forceinline__ void bsplit(float v, unsigned short* hi, unsigned short* lo) {
  __hip_bfloat16 h = __float2bfloat16(v);
  float hf = __bfloat162float(h);
  __hip_bfloat16 l = __float2bfloat16(v - hf);
  *hi = *reinterpret_cast<unsigned short*>(&h);
  *lo = *reinterpret_cast<unsigned short*>(&l);
}

// read 8 f32 from LDS row, split into hi/lo bf16 A-fragments (registers)
__device__ __forceinline__ void afrag(const float* row, short8* ah, short8* al) {
  float4 a = *(const float4*)row;
  float4 b = *(const float4*)(row + 4);
  unsigned short h, l;
  #pragma unroll
  for (int j = 0; j < 4; ++j) {
    bsplit((&a.x)[j], &h, &l); (*ah)[j]   = (short)h; (*al)[j]   = (short)l;
    bsplit((&b.x)[j], &h, &l); (*ah)[j+4] = (short)h; (*al)[j+4] = (short)l;
  }
}

// ---------------- wprep: dtype vote + weights->fp32 + MFMA B-fragment tables ------------
__global__ __launch_bounds__(256) void wprep_kernel(
    const void* nrm, const void* w1a, const void* b1a, const void* w1b,
    const void* b1b, const void* w2a, const void* b2a, const void* w2b,
    const void* b2b, const void* wc, const void* bc) {
  __shared__ int sflag;
  const int tid = threadIdx.x;
  if (tid < 64) {
    const float* nf = (const float*)nrm;
    const __hip_bfloat16* nh = (const __hip_bfloat16*)nrm;
    float x = nf[3*tid], y = nf[3*tid+1], z = nf[3*tid+2];
    float ss = x*x + y*y + z*z;
    bool okf = (ss > 0.98f && ss < 1.02f);
    float a = bf(nh[3*tid]), b2 = bf(nh[3*tid+1]), c2 = bf(nh[3*tid+2]);
    float sb = a*a + b2*b2 + c2*c2;
    bool okb = (sb > 0.95f && sb < 1.05f);
    unsigned long long mf = __ballot(okf), mb = __ballot(okb);
    if (tid == 0) {
      sflag = (__popcll(mf) >= __popcll(mb)) ? 1 : 0;
      g_isf32 = sflag;
    }
  }
  __syncthreads();
  const bool f32 = sflag != 0;
  for (int i = tid; i < 128;  i += 256) g_wts[OW1A + i] = ldf(w1a, i, f32);
  for (int i = tid; i < 32;   i += 256) g_wts[OB1A + i] = ldf(b1a, i, f32);
  for (int i = tid; i < 1024; i += 256) g_wts[OW1B + i] = ldf(w1b, i, f32);
  for (int i = tid; i < 32;   i += 256) g_wts[OB1B + i] = ldf(b1b, i, f32);
  for (int i = tid; i < 1152; i += 256) g_wts[OW2A + i] = ldf(w2a, i, f32);
  for (int i = tid; i < 32;   i += 256) g_wts[OB2A + i] = ldf(b2a, i, f32);
  for (int i = tid; i < 1024; i += 256) g_wts[OW2B + i] = ldf(w2b, i, f32);
  for (int i = tid; i < 32;   i += 256) g_wts[OB2B + i] = ldf(b2b, i, f32);
  for (int i = tid; i < 1280; i += 256) g_wts[OWC  + i] = ldf(wc,  i, f32);
  for (int i = tid; i < 40;   i += 256) g_wts[OBC  + i] = ldf(bc,  i, f32);
  // B-fragment tables (from raw inputs; independent of g_wts writes above)
  for (int i = tid; i < 4096; i += 256) {
    int which = i >> 11;                 // 0 = w1b, 1 = w2b
    int r = i & 2047;
    int t  = r >> 10;  r &= 1023;
    int hl = r >> 9;   r &= 511;
    int ln = r >> 3;
    int j  = r & 7;
    int k = (ln >> 4)*8 + j;
    int c = t*16 + (ln & 15);
    float wv = ldf(which ? w2b : w1b, k*CH + c, f32);
    unsigned short hi, lo;
    bsplit(wv, &hi, &lo);
    unsigned short v = hl ? lo : hi;
    if (which) g_wfrag2[t][hl][ln][j] = v;
    else       g_wfrag1[t][hl][ln][j] = v;
  }
}

// ---------------- prep: inputs -> float4 (pos.w = |p|^2 f32, filter only) ----------------
__global__ __launch_bounds__(256) void prep_kernel(const void* __restrict__ pos,
                                                   const void* __restrict__ nrm) {
  const bool f32 = g_isf32 != 0;
  int i = blockIdx.x*256 + threadIdx.x;
  float x = ldf(pos, 3*i, f32), y = ldf(pos, 3*i+1, f32), z = ldf(pos, 3*i+2, f32);
  float sq = x*x + y*y + z*z;
  g_pos4[i] = make_float4(x, y, z, sq);
  float a = ldf(nrm, 3*i, f32), b = ldf(nrm, 3*i+1, f32), c = ldf(nrm, 3*i+2, f32);
  g_nrm4[i] = make_float4(a, b, c, 0.f);
}

// ---------------- kNN: 512-thread blocks, SoA xyz tile, interleaved bisection -----------
// Structure validated R12-R19 (see prior rounds' comments).
__global__ __launch_bounds__(512) void knn_kernel() {
  __shared__ float sx[NN], sy[NN], sz[NN];          // 49152 B (SoA xyz tile)
  __shared__ unsigned short ilst[64][CAP];          // 12288 B
  __shared__ double dlst[8][CAP];                   //  6144 B
  __shared__ int    cnt[64];
  const int tid  = threadIdx.x;
  const int w    = tid >> 6, lane = tid & 63;
  const int blk  = blockIdx.x;
  const int b    = blk >> 6;                        // 64 blocks per batch
  const int qbw  = ((blk & 63) << 6) | (w << 3);    // first of this wave's 8 queries
  const float4* bp = g_pos4 + b*NN;

  #pragma unroll
  for (int k = 0; k < 8; ++k) {
    int idx = k*512 + tid;
    float4 o = bp[idx];
    sx[idx] = o.x; sy[idx] = o.y; sz[idx] = o.z;
  }
  __syncthreads();                                  // the only barrier

  float q2x[8], q2y[8], q2z[8];
  #pragma unroll
  for (int qq = 0; qq < 8; ++qq) {
    int qi = qbw + qq;
    q2x[qq] = -2.f*sx[qi]; q2y[qq] = -2.f*sy[qi]; q2z[qq] = -2.f*sz[qi];
  }

  float mn[8];
  #pragma unroll
  for (int qq = 0; qq < 8; ++qq) mn[qq] = BIG;
  #pragma unroll 4
  for (int it = 0; it < 64; ++it) {
    int idx = it*64 + lane;
    float ox = sx[idx], oy = sy[idx], oz = sz[idx];
    float ow = __builtin_fmaf(oz, oz, __builtin_fmaf(oy, oy, ox*ox));
    #pragma unroll
    for (int qq = 0; qq < 8; ++qq) {
      float d = __builtin_fmaf(q2x[qq], ox,
                __builtin_fmaf(q2y[qq], oy,
                __builtin_fmaf(q2z[qq], oz, ow)));
      mn[qq] = fminf(mn[qq], d);
    }
  }

  unsigned int key[8], lo[8], hi[8];
  #pragma unroll
  for (int qq = 0; qq < 8; ++qq) { key[qq] = fkey(mn[qq]); lo[qq] = 0u; hi[qq] = 0xFFFFFFFFu; }
  #pragma unroll 1
  for (int s = 0; s < 32; ++s) {
    #pragma unroll
    for (int qq = 0; qq < 8; ++qq) {
      unsigned int mid = lo[qq] + ((hi[qq] - lo[qq]) >> 1);
      int c = (int)__popcll(__ballot(key[qq] <= mid));
      if (c >= 17) hi[qq] = mid; else lo[qq] = mid + 1;
    }
  }
  float Tf[8];
  #pragma unroll
  for (int qq = 0; qq < 8; ++qq) {
    float T = funkey(hi[qq]);                       // exact 17th smallest
    Tf[qq] = T + 4e-5f + 1e-5f*fabsf(T);            // margin >> f32 d2' abs error
  }

  if (lane < 8) cnt[(w<<3) | lane] = 0;             // wave-private counters

  #pragma unroll 4
  for (int it = 0; it < 64; ++it) {
    int idx = it*64 + lane;
    float ox = sx[idx], oy = sy[idx], oz = sz[idx];
    float ow = __builtin_fmaf(oz, oz, __builtin_fmaf(oy, oy, ox*ox));
    #pragma unroll
    for (int qq = 0; qq < 8; ++qq) {
      float d = __builtin_fmaf(q2x[qq], ox,
                __builtin_fmaf(q2y[qq], oy,
                __builtin_fmaf(q2z[qq], oz, ow)));
      if (d <= Tf[qq] && idx != qbw + qq) {
        int p = atomicAdd(&cnt[(w<<3)|qq], 1);
        if (p < CAP) ilst[(w<<3)|qq][p] = (unsigned short)idx;
      }
    }
  }

  #pragma unroll 1
  for (int qq = 0; qq < 8; ++qq) {
    const int qi = qbw + qq;
    const int m = min(cnt[(w<<3)|qq], CAP);
    const double mx = (double)sx[qi], my_ = (double)sy[qi], mz = (double)sz[qi];
    const double sqme = (mx*mx + my_*my_) + mz*mz;
    for (int e = lane; e < m; e += 64) {
      int ci = ilst[(w<<3)|qq][e];
      double ox = (double)sx[ci], oy = (double)sy[ci], oz = (double)sz[ci];
      double sqo = (ox*ox + oy*oy) + oz*oz;
      double dt  = (mx*ox + my_*oy) + mz*oz;
      dlst[w][e] = (sqme + sqo) - 2.0*dt;
    }
    for (int e = lane; e < m; e += 64) {
      double myd = dlst[w][e];
      int myi = ilst[(w<<3)|qq][e];
      int rank = 0;
      for (int o = 0; o < m; ++o) {                 // broadcast LDS reads
        double od = dlst[w][o];
        int oi = ilst[(w<<3)|qq][o];
        rank += (od < myd) || (od == myd && oi < myi);
      }
      if (rank < KK) g_nbr[(b*NN + qi)*KK + rank] = b*NN + myi;
    }
  }
}

// ---------------- conv1: f32 LDS h + register-split MFMA, fused u epilogue --------------
// h rows packed TIGHTLY (row = edge index e = node*17+slot; no 32-row padding).
// A-frags built at read time: 2x ds_read_b128 f32 + 8 reg bsplits -> hi & lo frags.
// Tile0 rows = node's slots 0..15; tile1 row l15=0 = slot 16 (lanes l15>0 read the
// NEXT node's rows -- garbage lands in C rows 1..15 which are never consumed; MFMA
// rows are independent). h1s has 152 rows so node 7's tile1 reads stay in-bounds.
// 3-term split (hi*hi+hi*lo+lo*hi) as validated R19 (absmax unchanged vs scalar).
__global__ __launch_bounds__(256) void conv1_kernel() {
  __shared__ __align__(16) float fe[136][4];        //  2176 B
  __shared__ __align__(16) float h1s[152*HROW];     // 21888 B
  __shared__ __align__(16) float wsaT[32*HROW];     //  4608 B (w2a[0:32] as [c][k])
  __shared__ float xs[8][CH];
  const int tid = threadIdx.x;
  const int c = tid & 31;
  const int lane = tid & 63, wv = tid >> 6;
  const int quad = lane >> 4, l15 = lane & 15;
  const int node0 = blockIdx.x << 3;
  float w1a_c[4];
  #pragma unroll
  for (int f = 0; f < 4; ++f) w1a_c[f] = g_wts[OW1A + f*CH + c];
  const float b1a_c = g_wts[OB1A + c];
  short8 bH0 = *(const short8*)&g_wfrag1[0][0][lane][0];
  short8 bL0 = *(const short8*)&g_wfrag1[0][1][lane][0];
  short8 bH1 = *(const short8*)&g_wfrag1[1][0][lane][0];
  short8 bL1 = *(const short8*)&g_wfrag1[1][1][lane][0];
  const float bias0 = g_wts[OB1B + l15];
  const float bias1 = g_wts[OB1B + 16 + l15];

  for (int i = tid; i < 1024; i += 256) {           // stage w2a[0:32] transposed
    int k = i >> 5, cc = i & 31;
    wsaT[cc*HROW + k] = g_wts[OW2A + i];
  }
  if (tid < 136) {
    int ns = tid / 17, slot = tid - ns*17;
    int i = node0 + ns;
    int j = (slot < KK) ? g_nbr[i*KK + slot] : i;   // slot 16 = self-loop
    ppf4(g_pos4[i], g_nrm4[i], g_pos4[j], g_nrm4[j], fe[tid]);
  }
  __syncthreads();
  #pragma unroll
  for (int it = 0; it < 17; ++it) {                 // h-phase: f32, single store
    int idx = it*256 + tid;
    int e = idx >> 5;                               // c == tid&31; row == e
    float4 f4 = *(const float4*)fe[e];
    float h = b1a_c + f4.x*w1a_c[0] + f4.y*w1a_c[1] + f4.z*w1a_c[2] + f4.w*w1a_c[3];
    h1s[e*HROW + c] = fmaxf(h, 0.f);
  }
  __syncthreads();
  #pragma unroll
  for (int ni = 0; ni < 2; ++ni) {                  // MFMA phase: 2 nodes/wave
    const int n8 = wv*2 + ni;
    const int rbase = n8*17;
    short8 ah0, al0, ah1, al1;
    afrag(&h1s[(rbase      + l15)*HROW + quad*8], &ah0, &al0);
    afrag(&h1s[(rbase + 16 + l15)*HROW + quad*8], &ah1, &al1);
    f32x4 a00 = {0.f,0.f,0.f,0.f}, a01 = a00, a10 = a00, a11 = a00;
    a00 = __builtin_amdgcn_mfma_f32_16x16x32_bf16(ah0, bH0, a00, 0, 0, 0);
    a00 = __builtin_amdgcn_mfma_f32_16x16x32_bf16(ah0, bL0, a00, 0, 0, 0);
    a00 = __builtin_amdgcn_mfma_f32_16x16x32_bf16(al0, bH0, a00, 0, 0, 0);
    a01 = __builtin_amdgcn_mfma_f32_16x16x32_bf16(ah0, bH1, a01, 0, 0, 0);
    a01 = __builtin_amdgcn_mfma_f32_16x16x32_bf16(ah0, bL1, a01, 0, 0, 0);
    a01 = __builtin_amdgcn_mfma_f32_16x16x32_bf16(al0, bH1, a01, 0, 0, 0);
    a10 = __builtin_amdgcn_mfma_f32_16x16x32_bf16(ah1, bH0, a10, 0, 0, 0);
    a10 = __builtin_amdgcn_mfma_f32_16x16x32_bf16(ah1, bL0, a10, 0, 0, 0);
    a10 = __builtin_amdgcn_mfma_f32_16x16x32_bf16(al1, bH0, a10, 0, 0, 0);
    a11 = __builtin_amdgcn_mfma_f32_16x16x32_bf16(ah1, bH1, a11, 0, 0, 0);
    a11 = __builtin_amdgcn_mfma_f32_16x16x32_bf16(ah1, bL1, a11, 0, 0, 0);
    a11 = __builtin_amdgcn_mfma_f32_16x16x32_bf16(al1, bH1, a11, 0, 0, 0);
    float m0 = fmaxf(fmaxf(a00[0], a00[1]), fmaxf(a00[2], a00[3]));
    float m1 = fmaxf(fmaxf(a01[0], a01[1]), fmaxf(a01[2], a01[3]));
    if (quad == 0) { m0 = fmaxf(m0, a10[0]); m1 = fmaxf(m1, a11[0]); }
    m0 = fmaxf(m0, __shfl_xor(m0, 16)); m0 = fmaxf(m0, __shfl_xor(m0, 32));
    m1 = fmaxf(m1, __shfl_xor(m1, 16)); m1 = fmaxf(m1, __shfl_xor(m1, 32));
    if (quad == 0) {
      xs[n8][l15]      = fmaxf(m0 + bias0, 0.f);    // x1 = relu(max + b1b)
      xs[n8][16 + l15] = fmaxf(m1 + bias1, 0.f);
    }
  }
  __syncthreads();
  const int ns = tid >> 5;
  float uu = 0.f;
  #pragma unroll
  for (int k4 = 0; k4 < 8; ++k4) {
    float4 x4 = *(const float4*)&xs[ns][4*k4];
    float4 w4 = *(const float4*)&wsaT[c*HROW + 4*k4];
    uu += x4.x*w4.x + x4.y*w4.y + x4.z*w4.z + x4.w*w4.w;
  }
  g_u[(node0 + ns)*CH + c] = uu;              // u = x1 @ w2a[0:32,:]
}

// ---------------- conv2: f32 LDS h + register-split MFMA + block-max -> g_bmax ----------
__global__ __launch_bounds__(256) void conv2_kernel() {
  __shared__ __align__(16) float fe[136][4];
  __shared__ int jn[136];
  __shared__ __align__(16) float h1s[152*HROW];
  __shared__ float xs[8][CH];
  const int tid = threadIdx.x;
  const int c = tid & 31;
  const int lane = tid & 63, wv = tid >> 6;
  const int quad = lane >> 4, l15 = lane & 15;
  const int node0 = blockIdx.x << 3;
  float w2aL_c[4];
  #pragma unroll
  for (int f = 0; f < 4; ++f) w2aL_c[f] = g_wts[OW2A + (CH + f)*CH + c];
  const float b2a_c = g_wts[OB2A + c];
  short8 bH0 = *(const short8*)&g_wfrag2[0][0][lane][0];
  short8 bL0 = *(const short8*)&g_wfrag2[0][1][lane][0];
  short8 bH1 = *(const short8*)&g_wfrag2[1][0][lane][0];
  short8 bL1 = *(const short8*)&g_wfrag2[1][1][lane][0];
  const float bias0 = g_wts[OB2B + l15];
  const float bias1 = g_wts[OB2B + 16 + l15];

  if (tid < 136) {
    int ns = tid / 17, slot = tid - ns*17;
    int i = node0 + ns;
    int j = (slot < KK) ? g_nbr[i*KK + slot] : i;
    jn[tid] = j;
    ppf4(g_pos4[i], g_nrm4[i], g_pos4[j], g_nrm4[j], fe[tid]);
  }
  __syncthreads();
  #pragma unroll
  for (int it = 0; it < 17; ++it) {
    int idx = it*256 + tid;
    int e = idx >> 5;
    float4 f4 = *(const float4*)fe[e];
    float uv = g_u[jn[e]*CH + c];             // x_j @ w2a[0:32] precomputed
    float h = b2a_c + uv + f4.x*w2aL_c[0] + f4.y*w2aL_c[1] + f4.z*w2aL_c[2] + f4.w*w2aL_c[3];
    h1s[e*HROW + c] = fmaxf(h, 0.f);
  }
  __syncthreads();
  #pragma unroll
  for (int ni = 0; ni < 2; ++ni) {
    const int n8 = wv*2 + ni;
    const int rbase = n8*17;
    short8 ah0, al0, ah1, al1;
    afrag(&h1s[(rbase      + l15)*HROW + quad*8], &ah0, &al0);
    afrag(&h1s[(rbase + 16 + l15)*HROW + quad*8], &ah1, &al1);
    f32x4 a00 = {0.f,0.f,0.f,0.f}, a01 = a00, a10 = a00, a11 = a00;
    a00 = __builtin_amdgcn_mfma_f32_16x16x32_bf16(ah0, bH0, a00, 0, 0, 0);
    a00 = __builtin_amdgcn_mfma_f32_16x16x32_bf16(ah0, bL0, a00, 0, 0, 0);
    a00 = __builtin_amdgcn_mfma_f32_16x16x32_bf16(al0, bH0, a00, 0, 0, 0);
    a01 = __builtin_amdgcn_mfma_f32_16x16x32_bf16(ah0, bH1, a01, 0, 0, 0);
    a01 = __builtin_amdgcn_mfma_f32_16x16x32_bf16(ah0, bL1, a01, 0, 0, 0);
    a01 = __builtin_amdgcn_mfma_f32_16x16x32_bf16(al0, bH1, a01, 0, 0, 0);
    a10 = __builtin_amdgcn_mfma_f32_16x16x32_bf16(ah1, bH0, a10, 0, 0, 0);
    a10 = __builtin_amdgcn_mfma_f32_16x16x32_bf16(ah1, bL0, a10, 0, 0, 0);
    a10 = __builtin_amdgcn_mfma_f32_16x16x32_bf16(al1, bH0, a10, 0, 0, 0);
    a11 = __builtin_amdgcn_mfma_f32_16x16x32_bf16(ah1, bH1, a11, 0, 0, 0);
    a11 = __builtin_amdgcn_mfma_f32_16x16x32_bf16(ah1, bL1, a11, 0, 0, 0);
    a11 = __builtin_amdgcn_mfma_f32_16x16x32_bf16(al1, bH1, a11, 0, 0, 0);
    float m0 = fmaxf(fmaxf(a00[0], a00[1]), fmaxf(a00[2], a00[3]));
    float m1 = fmaxf(fmaxf(a01[0], a01[1]), fmaxf(a01[2], a01[3]));
    if (quad == 0) { m0 = fmaxf(m0, a10[0]); m1 = fmaxf(m1, a11[0]); }
    m0 = fmaxf(m0, __shfl_xor(m0, 16)); m0 = fmaxf(m0, __shfl_xor(m0, 32));
    m1 = fmaxf(m1, __shfl_xor(m1, 16)); m1 = fmaxf(m1, __shfl_xor(m1, 32));
    if (quad == 0) {
      xs[n8][l15]      = fmaxf(m0 + bias0, 0.f);    // x2 = relu(max + b2b)
      xs[n8][16 + l15] = fmaxf(m1 + bias1, 0.f);
    }
  }
  __syncthreads();
  if (tid < CH) {                             // block max -> plain coalesced store
    float m2 = xs[0][c];
    #pragma unroll
    for (int r = 1; r < 8; ++r) m2 = fmaxf(m2, xs[r][c]);
    g_bmax[blockIdx.x*CH + c] = m2;
  }
}

// ---------------- head: two-stage max over g_bmax + 32->40 matmul (f32 out) -------------
__global__ __launch_bounds__(256) void head_kernel(float* __restrict__ out) {
  __shared__ float red[8][CH];
  __shared__ float gm[CH];
  const int g = blockIdx.x;
  const int c = threadIdx.x & 31, sub = threadIdx.x >> 5;
  const float* base = g_bmax + (size_t)(g*512 + sub*64)*CH;   // 512 conv2 blocks/graph
  float mx = 0.f;                                             // x2 >= 0 (relu)
  #pragma unroll
  for (int n = 0; n < 64; ++n) mx = fmaxf(mx, base[n*CH + c]);
  red[sub][c] = mx;
  __syncthreads();
  if (threadIdx.x < CH) {
    float m2 = red[0][c];
    #pragma unroll
    for (int r = 1; r < 8; ++r) m2 = fmaxf(m2, red[r][c]);
    gm[c] = m2;
  }
  __syncthreads();
  if (threadIdx.x < NCLS) {
    int co = threadIdx.x;
    float s = g_wts[OBC + co];
    #pragma unroll
    for (int f = 0; f < CH; ++f) s += gm[f] * g_wts[OWC + f*NCLS + co];
    out[g*NCLS + co] = s;                     // float32 out (reference dtype)
  }
}

extern "C" void kernel_launch(void* const* d_in, const int* in_sizes, int n_in,
                              void* d_out, int out_size, void* d_ws, size_t ws_size,
                              hipStream_t stream) {
  const void* pos = d_in[0];
  const void* nrm = d_in[1];
  // d_in[2] = batch (int32) -- unused, batches are uniform
  const void* w1a = d_in[3];
  const void* b1a = d_in[4];
  const void* w1b = d_in[5];
  const void* b1b = d_in[6];
  const void* w2a = d_in[7];
  const void* b2a = d_in[8];
  const void* w2b = d_in[9];
  const void* b2b = d_in[10];
  const void* wc  = d_in[11];
  const void* bc  = d_in[12];

  wprep_kernel<<<1,      256, 0, stream>>>(nrm, w1a, b1a, w1b, b1b, w2a, b2a, w2b, b2b, wc, bc);
  prep_kernel <<<MM/256, 256, 0, stream>>>(pos, nrm);
  knn_kernel  <<<MM/64,  512, 0, stream>>>();
  conv1_kernel<<<MM/8,   256, 0, stream>>>();
  conv2_kernel<<<MM/8,   256, 0, stream>>>();
  head_kernel <<<NB,     256, 0, stream>>>((float*)d_out);
}